// Round 2
// baseline (2139.400 us; speedup 1.0000x reference)
//
#include <hip/hip_runtime.h>
#include <hip/hip_bf16.h>
#include <math.h>
#include <stdint.h>

typedef __hip_bfloat16 bf16;
typedef __attribute__((ext_vector_type(8))) short short8;
typedef __attribute__((ext_vector_type(4))) short short4v;
typedef __attribute__((ext_vector_type(4))) float f32x4;

#define CC 66      // channels = J*DIMS
#define TT 100     // time steps
#define JJ 22      // joints
#define HH 8       // heads
#define HD 64      // head dim
#define EE 512     // embed
#define CPAD 101   // comb LDS stride in k_epi / k_fused

// padded token layouts in ws (zero-padded so MFMA K-chunks read clean zeros)
#define SPT_R 112  // spT rows (>=100, mult of 16)
#define SPT_S 96   // spT stride (>=66, mult of 32 for k-chunks)
#define TP_R 80    // tp rows (>=66)
#define TP_S 128   // tp stride (>=100)

// weight section offsets (bf16 elements) inside ws
#define W_STWK 0                    // [512][128]
#define W_STWV 65536                // [512][128]
#define W_STWQ 131072               // [512][96]
#define W_STWO 180224               // [80][512]
#define W_TSWK 221184               // [512][96]
#define W_TSWV 270336               // [512][96]
#define W_TSWQ 319488               // [512][128]
#define W_TSWO 385024               // [112][512]
#define W_TOTAL 442368

__device__ __forceinline__ float b2f(bf16 v){ return __bfloat162float(v); }
__device__ __forceinline__ bf16 f2b(float v){ return __float2bfloat16(v); }
__device__ __forceinline__ short sb(float v){ __hip_bfloat16 h = __float2bfloat16(v); return *(short*)&h; }
__device__ __forceinline__ float fb(short s){ __hip_bfloat16 h; *(short*)&h = s; return __bfloat162float(h); }

// ---------------------------------------------------------------- k_tr
__global__ void k_tr(const float* __restrict__ src, bf16* __restrict__ dst,
                     int Rsrc, int Csrc, int JP, int IP)
{
  int o = blockIdx.x*256 + threadIdx.x;
  if (o >= JP*IP) return;
  int j = o / IP, i = o - j*IP;
  float v = (j < Csrc && i < Rsrc) ? src[(long)i*Csrc + j] : 0.f;
  dst[o] = f2b(v);
}

// ---------------------------------------------------------------- k_prep
__global__ __launch_bounds__(256) void k_prep(
    const float* __restrict__ x, const float* __restrict__ adj,
    const float* __restrict__ sadj, const float* __restrict__ tmask,
    const float* __restrict__ tadj,
    bf16* __restrict__ spT_all, bf16* __restrict__ tp_all)
{
  __shared__ float s_x[CC*TT];
  __shared__ float s_Mt[TT*TT];
  __shared__ float s_A[JJ*JJ];
  __shared__ float s_dis[JJ];
  const int b = blockIdx.x, tid = threadIdx.x;
  const long bb = (long)b * (CC*TT);

  if (tid < JJ) {
    float dsum = 0.f;
    for (int i = 0; i < JJ; ++i) dsum += adj[tid*JJ + i];
    s_dis[tid] = dsum > 0.f ? rsqrtf(dsum) : 0.f;
  }
  for (int o = tid; o < CC*TT; o += 256) s_x[o] = x[bb + o];
  for (int o = tid; o < TT*TT; o += 256) {
    int f = o / TT, t = o - f*TT;
    s_Mt[t*TT + f] = tadj[o] * tmask[o];
  }
  __syncthreads();
  for (int o = tid; o < JJ*JJ; o += 256) {
    int v = o / JJ, j = o - v*JJ;
    s_A[o] = sadj[o] * adj[o] * s_dis[v] * s_dis[j];
  }
  __syncthreads();

  bf16* spT = spT_all + (long)b * (SPT_R*SPT_S);
  bf16* tp  = tp_all  + (long)b * (TP_R*TP_S);

  for (int o = tid; o < SPT_R*SPT_S; o += 256) {
    int t = o / SPT_S, c = o - t*SPT_S;
    float acc = 0.f;
    if (t < TT && c < CC) {
      int v = c / 3, dd = c - v*3;
      for (int j = 0; j < JJ; ++j) acc += s_A[v*JJ + j] * s_x[(j*3 + dd)*TT + t];
    }
    spT[o] = f2b(acc);
  }
  for (int o = tid; o < TP_R*TP_S; o += 256) {
    int n = o / TP_S, f = o - n*TP_S;
    float acc = 0.f;
    if (n < CC && f < TT) {
      float a0 = 0.f, a1 = 0.f;
      for (int t = 0; t < TT; t += 2) {
        a0 += s_x[n*TT + t    ] * s_Mt[(t    )*TT + f];
        a1 += s_x[n*TT + t + 1] * s_Mt[(t + 1)*TT + f];
      }
      acc = a0 + a1;
    }
    tp[o] = f2b(acc);
  }
}

// ---------------------------------------------------------------- MFMA helper
// Compile-time tile counts, strides and swizzle flags.
// A[m=lane&15][k=quad*8+j]; B[n=lane&15][k=quad*8+j]; D col=lane&15,row=quad*4+reg.
// Swizzled arrays use logical stride SA/SB/SD with col XOR ((row&7)<<3) at
// 8-short granularity (keeps 16B alignment; 2-way bank spread on b128 reads).
template<int Mt, int Nt, int KCH, int SA, int SB, int SD, bool SWA, bool SWB, bool SWD>
__device__ __forceinline__ void mm_tiles_t(
    const short* __restrict__ Am, const short* __restrict__ Bm,
    short* __restrict__ D, const float* __restrict__ bias, float scale,
    int wave, int ln, int qd)
{
  constexpr int NTILE = Mt*Nt;
  constexpr int NU = (NTILE + 7) / 8;
  #pragma unroll
  for (int u = 0; u < NU; ++u) {
    int ti = u*8 + wave;
    if (ti < NTILE) {
      int mi = ti / Nt, ni = ti - mi*Nt;
      f32x4 acc = {0.f, 0.f, 0.f, 0.f};
      const int ar = mi*16 + ln, br = ni*16 + ln;
      const int sza = SWA ? ((ar&7)<<3) : 0;
      const int szb = SWB ? ((br&7)<<3) : 0;
      const short* ap = Am + (long)ar*SA;
      const short* bp = Bm + (long)br*SB;
      #pragma unroll
      for (int kc = 0; kc < KCH; ++kc) {
        short8 af = *(const short8*)(ap + ((qd*8 + kc*32) ^ sza));
        short8 bf = *(const short8*)(bp + ((qd*8 + kc*32) ^ szb));
        acc = __builtin_amdgcn_mfma_f32_16x16x32_bf16(af, bf, acc, 0, 0, 0);
      }
      int col = ni*16 + ln;
      float bv_ = bias ? bias[col] : 0.f;
      #pragma unroll
      for (int r = 0; r < 4; ++r) {
        int row = mi*16 + qd*4 + r;
        int cs = SWD ? (col ^ ((row&7)<<3)) : col;
        D[row*SD + cs] = sb((acc[r] + bv_) * scale);
      }
    }
  }
}

// ---------------------------------------------------------------- attn body
// A=0: q = spatial tokens (100), kv = temporal (66)
// A=1: q = temporal tokens (66), kv = spatial (100)
// Zone plan (per head):
//   P1: K -> Z1 (swz64), Q -> Z2 (swz64)            [global operands]
//   P2: S = Q.K -> Pm (plain, padded stride)
//   P3: V^T -> Z2 (Q dead) + zero V^T pad cols; softmax(Pm)
//   P4: O = P.V -> Z1 (K dead)  (swz64)
//   P5: Oproj: accO += O @ woT  (Z1 swz64, woT global)
// 5 barriers/head; LDS = Z1 14336B + Z2 16384B + Pm 23296B = 54016B -> 3 blk/CU.
template<int A>
__device__ __forceinline__ void attn_body(
    short* __restrict__ Z1, short* __restrict__ Z2, short* __restrict__ Pm,
    const bf16* __restrict__ spT_all, const bf16* __restrict__ tp_all,
    const bf16* __restrict__ wsec,
    const float* __restrict__ st_bq, const float* __restrict__ st_bv,
    const float* __restrict__ ts_bq, const float* __restrict__ ts_bv,
    float* __restrict__ o1, float* __restrict__ o2, float* __restrict__ comb_g,
    int plain)
{
  constexpr int QROWS = A ? 66 : 100;
  constexpr int KROWS = A ? 100 : 66;
  constexpr int MQ  = A ? 5 : 7;
  constexpr int MK  = A ? 7 : 5;
  constexpr int QCH = A ? 4 : 3;   // q-projection k-chunks
  constexpr int KCH = A ? 3 : 4;   // k/v-projection k-chunks
  constexpr int PCH = A ? 4 : 3;   // PV k-chunks
  constexpr int SAQ = A ? TP_S : SPT_S;
  constexpr int SAK = A ? SPT_S : TP_S;
  constexpr int PS  = A ? 136 : 104;   // Pm stride (padded, 2-way banks)
  constexpr int PR  = A ? 80  : 112;   // Pm rows
  constexpr int VTS = A ? 128 : 104;   // V^T stride inside Z2
  constexpr bool VSW = A ? true : false; // V^T swizzled only for A=1 (stride 128)

  const int b = blockIdx.x >> 1, tid = threadIdx.x;
  const long bb = (long)b * (CC*TT);
  const int wave = tid >> 6, lane = tid & 63, ln = lane & 15, qd = lane >> 4;

  const short* Aq = (const short*)(A ? (tp_all  + (long)b*TP_R*TP_S)
                                     : (spT_all + (long)b*SPT_R*SPT_S));
  const short* Ak = (const short*)(A ? (spT_all + (long)b*SPT_R*SPT_S)
                                     : (tp_all  + (long)b*TP_R*TP_S));
  const short* wqT = (const short*)(wsec + (A ? W_TSWQ : W_STWQ));
  const short* wkT = (const short*)(wsec + (A ? W_TSWK : W_STWK));
  const short* wvT = (const short*)(wsec + (A ? W_TSWV : W_STWV));
  const short* woT = (const short*)(wsec + (A ? W_TSWO : W_STWO));
  const float* bq = A ? ts_bq : st_bq;
  const float* bv = A ? ts_bv : st_bv;

  // zero-init Pm once (pad columns beyond written range must stay zero)
  for (int o = tid; o < PR*PS; o += 512) Pm[o] = 0;
  __syncthreads();

  f32x4 accO[5];
  { f32x4 z = {0.f,0.f,0.f,0.f}; for (int i = 0; i < 5; ++i) accO[i] = z; }

  for (int h = 0; h < HH; ++h) {
    const int base = h*HD;
    // P1: K -> Z1, Q -> Z2 (both from global, swizzled stride-64 zones)
    mm_tiles_t<MK,4,KCH, SAK,SAK,64, false,false,true>(
        Ak, wkT + (long)base*SAK, Z1, nullptr, 1.f, wave, ln, qd);
    mm_tiles_t<MQ,4,QCH, SAQ,SAQ,64, false,false,true>(
        Aq, wqT + (long)base*SAQ, Z2, bq + base, 1.f, wave, ln, qd);
    __syncthreads();
    // P2: S = Q @ K^T * 1/8  -> Pm
    mm_tiles_t<MQ,MK,2, 64,64,PS, true,true,false>(
        Z2, Z1, Pm, nullptr, 0.125f, wave, ln, qd);
    __syncthreads();
    // P3: V^T -> Z2 (Q dead); zero V^T pad cols; softmax(Pm) in parallel
    mm_tiles_t<4,MK,KCH, SAK,SAK,VTS, false,false,VSW>(
        wvT + (long)base*SAK, Ak, Z2, nullptr, 1.f, wave, ln, qd);
    {
      constexpr int C0 = A ? 112 : 80;   // first pad col to zero
      for (int o = tid; o < 64*16; o += 512) {
        int d = o >> 4, c = C0 + (o & 15);
        int cs = VSW ? (c ^ ((d&7)<<3)) : c;
        Z2[d*VTS + cs] = 0;
      }
    }
    // wave-parallel softmax: 4 lanes per row, exp kept in registers
    {
      const int r = tid >> 2, sub = tid & 3;
      constexpr int NCH  = (KROWS + 3) / 4;   // short4 chunks per row
      constexpr int PERL = (NCH + 3) / 4;     // chunks per lane
      if (r < QROWS) {
        short* pr = Pm + r*PS;
        float v[PERL*4];
        float mx = -1e30f;
        #pragma unroll
        for (int u = 0; u < PERL; ++u) {
          int j4 = sub + u*4;
          float f0 = -1e30f, f1 = -1e30f, f2 = -1e30f, f3 = -1e30f;
          if (j4 < NCH) {
            short4v q4 = ((const short4v*)pr)[j4];
            int base0 = j4*4;
            f0 = fb(q4.x);
            f1 = (base0+1 < KROWS) ? fb(q4.y) : -1e30f;
            f2 = (base0+2 < KROWS) ? fb(q4.z) : -1e30f;
            f3 = (base0+3 < KROWS) ? fb(q4.w) : -1e30f;
          }
          v[u*4+0]=f0; v[u*4+1]=f1; v[u*4+2]=f2; v[u*4+3]=f3;
          mx = fmaxf(mx, fmaxf(fmaxf(f0,f1), fmaxf(f2,f3)));
        }
        mx = fmaxf(mx, __shfl_xor(mx, 1));
        mx = fmaxf(mx, __shfl_xor(mx, 2));
        float sum = 0.f;
        #pragma unroll
        for (int i = 0; i < PERL*4; ++i) { float p = __expf(v[i]-mx); v[i] = p; sum += p; }
        sum += __shfl_xor(sum, 1);
        sum += __shfl_xor(sum, 2);
        float rs = 1.f / sum;
        #pragma unroll
        for (int u = 0; u < PERL; ++u) {
          int j4 = sub + u*4;
          if (j4 < NCH) {
            short4v w4;
            w4.x = sb(v[u*4+0]*rs); w4.y = sb(v[u*4+1]*rs);
            w4.z = sb(v[u*4+2]*rs); w4.w = sb(v[u*4+3]*rs);
            ((short4v*)pr)[j4] = w4;
          }
        }
      }
    }
    __syncthreads();
    // P4: O = P @ V + bv  -> Z1 (K dead)
    mm_tiles_t<MQ,4,PCH, PS,VTS,64, false,VSW,true>(
        Pm, Z2, Z1, bv + base, 1.f, wave, ln, qd);
    __syncthreads();
    // P5: accO += O @ wo  (A = Z1 swizzled, B = global pre-transposed woT)
    #pragma unroll
    for (int u = 0; u < 5; ++u) {
      int ti = u*8 + wave;
      if (ti < MQ*MK) {
        int mi = ti / MK, ni = ti - mi*MK;
        const int ar = mi*16 + ln;
        const int sza = (ar&7)<<3;
        const short* ap = Z1 + ar*64;
        const short* bp = woT + (long)(ni*16 + ln)*512 + base + qd*8;
        f32x4 acc = accO[u];
        acc = __builtin_amdgcn_mfma_f32_16x16x32_bf16(
                *(const short8*)(ap + ((qd*8     ) ^ sza)),
                *(const short8*)bp, acc, 0,0,0);
        acc = __builtin_amdgcn_mfma_f32_16x16x32_bf16(
                *(const short8*)(ap + ((qd*8 + 32) ^ sza)),
                *(const short8*)(bp+32), acc, 0,0,0);
        accO[u] = acc;
      }
    }
    __syncthreads();   // protect Z1/Z2 before next head's P1
  }

  // accumulated out-proj -> per-flavor buffer (plain) or comb (atomic)
  #pragma unroll
  for (int u = 0; u < 5; ++u) {
    int ti = u*8 + wave;
    if (ti < MQ*MK) {
      int mi = ti / MK, ni = ti - mi*MK;
      int col = ni*16 + ln;
      #pragma unroll
      for (int r = 0; r < 4; ++r) {
        int row = mi*16 + qd*4 + r;
        if (row < QROWS && col < KROWS) {
          if (plain) {
            if (A) o2[bb + (long)row*TT + col] = accO[u][r];   // [c][t]
            else   o1[bb + (long)row*CC + col] = accO[u][r];   // [t][c]
          } else {
            long off = A ? ((long)row*TT + col) : ((long)col*TT + row);
            atomicAdd(&comb_g[bb + off], accO[u][r]);
          }
        }
      }
    }
  }
}

// ---------------------------------------------------------------- k_attn
// LDS 54,016 B and launch_bounds(512,6) -> VGPR<=84 -> 3 blocks/CU.
__global__ __launch_bounds__(512, 6) void k_attn(
    const bf16* __restrict__ spT_all, const bf16* __restrict__ tp_all,
    const bf16* __restrict__ wsec,
    const float* __restrict__ st_bq, const float* __restrict__ st_bv,
    const float* __restrict__ ts_bq, const float* __restrict__ ts_bv,
    float* __restrict__ o1, float* __restrict__ o2,
    float* __restrict__ comb_g, int plain)
{
  __shared__ __align__(16) short Z1[112*64];   // K then O        14336 B
  __shared__ __align__(16) short Z2[64*128];   // Q then V^T      16384 B
  __shared__ __align__(16) short Pm[112*104];  // S/P             23296 B
  if (blockIdx.x & 1)
    attn_body<1>(Z1,Z2,Pm,spT_all,tp_all,wsec,st_bq,st_bv,ts_bq,ts_bv,o1,o2,comb_g,plain);
  else
    attn_body<0>(Z1,Z2,Pm,spT_all,tp_all,wsec,st_bq,st_bv,ts_bq,ts_bv,o1,o2,comb_g,plain);
}

// ---------------------------------------------------------------- k_epi
__global__ __launch_bounds__(256) void k_epi(
    const float* __restrict__ comb_g,
    const float* __restrict__ c1, const float* __restrict__ c2,
    const float* __restrict__ x,
    const float* __restrict__ st_bo, const float* __restrict__ ts_bo,
    const float* __restrict__ alpha, const float* __restrict__ beta,
    const float* __restrict__ fcw, const float* __restrict__ fcb,
    float* __restrict__ out, int plain)
{
  __shared__ float s_cb[CC*CPAD];
  __shared__ float s_w[TT*TT];
  const int b = blockIdx.x, tid = threadIdx.x;
  const long bb = (long)b * (CC*TT);

  for (int o = tid; o < CC*TT; o += 256) {
    int c = o / TT, t = o - c*TT;
    float v;
    if (plain) v = c1[bb + (long)t*CC + c] + c2[bb + o];
    else       v = comb_g[bb + o];
    s_cb[c*CPAD + t] = v + st_bo[c] + ts_bo[t];
  }
  for (int o = tid; o < TT*TT; o += 256) {
    int f = o / TT, t = o - f*TT;
    s_w[t*TT + f] = fcw[o];
  }
  __syncthreads();
  // LN over channels: 2 lanes per t-column (200 threads), shfl_xor combine
  if (tid < 2*TT) {
    const int t = tid >> 1, hf = tid & 1;
    float part = 0.f;
    for (int c = hf; c < CC; c += 2) part += s_cb[c*CPAD + t];
    float mean = (part + __shfl_xor(part, 1)) * (1.f/CC);
    float vp = 0.f;
    for (int c = hf; c < CC; c += 2) { float dv = s_cb[c*CPAD + t] - mean; vp += dv*dv; }
    float var = (vp + __shfl_xor(vp, 1)) * (1.f/CC);
    float rstd = 1.f / sqrtf(var + 1e-5f);
    for (int c = hf; c < CC; c += 2) {
      float y = (s_cb[c*CPAD + t] - mean) * rstd * alpha[c] + beta[c];
      s_cb[c*CPAD + t] = y + x[bb + c*TT + t];
    }
  }
  __syncthreads();
  for (int o = tid; o < CC*TT; o += 256) {
    int c = o / TT, f = o - c*TT;
    const float* cr = s_cb + c*CPAD;
    float a0 = 0.f, a1 = 0.f;
    for (int t = 0; t < TT; t += 2) {
      a0 += cr[t    ] * s_w[(t    )*TT + f];
      a1 += cr[t + 1] * s_w[(t + 1)*TT + f];
    }
    out[bb + o] = tanhf(a0 + a1 + fcb[f]);
  }
}

// ---------------------------------------------------------------- R4 fallback
__global__ __launch_bounds__(128) void k_fused(
    const float* __restrict__ x, const float* __restrict__ adj,
    const float* __restrict__ sadj, const float* __restrict__ tmask,
    const float* __restrict__ tadj,
    const float* __restrict__ st_wq, const float* __restrict__ st_bq,
    const float* __restrict__ st_wk, const float* __restrict__ st_bk,
    const float* __restrict__ st_wv, const float* __restrict__ st_bv,
    const float* __restrict__ st_wo, const float* __restrict__ st_bo,
    const float* __restrict__ ts_wq, const float* __restrict__ ts_bq,
    const float* __restrict__ ts_wk, const float* __restrict__ ts_bk,
    const float* __restrict__ ts_wv, const float* __restrict__ ts_bv,
    const float* __restrict__ ts_wo, const float* __restrict__ ts_bo,
    const float* __restrict__ alpha, const float* __restrict__ beta,
    const float* __restrict__ fcw, const float* __restrict__ fcb,
    float* __restrict__ out)
{
  __shared__ float s_sp[CC*TT];
  __shared__ float s_tp[CC*TT];
  __shared__ __align__(16) float s_kv[2*TT*HD];
  __shared__ float s_comb[CC*CPAD];
  __shared__ float s_A[JJ*JJ];
  __shared__ float s_dis[JJ];

  const int b = blockIdx.x, tid = threadIdx.x;
  const long bb = (long)b * (CC*TT);
  float* s_xs = s_comb;
  float* s_Mt = s_kv;

  if (tid < JJ) {
    float dsum = 0.f;
    for (int i = 0; i < JJ; ++i) dsum += adj[tid*JJ + i];
    s_dis[tid] = dsum > 0.f ? rsqrtf(dsum) : 0.f;
  }
  for (int o = tid; o < CC*TT; o += 128) s_xs[o] = x[bb + o];
  for (int o = tid; o < TT*TT; o += 128) {
    int f = o / TT, t = o - f*TT;
    s_Mt[t*TT + f] = tadj[o] * tmask[o];
  }
  __syncthreads();
  for (int o = tid; o < JJ*JJ; o += 128) {
    int v = o / JJ, j = o - v*JJ;
    s_A[o] = sadj[o] * adj[o] * s_dis[v] * s_dis[j];
  }
  __syncthreads();

  for (int o = tid; o < CC*TT; o += 128) {
    int c = o / TT, t = o - c*TT, v = c / 3, dd = c - v*3;
    float acc = 0.f;
    for (int j = 0; j < JJ; ++j) acc += s_A[v*JJ + j] * s_xs[(j*3 + dd)*TT + t];
    s_sp[o] = acc;
  }
  for (int o = tid; o < CC*TT; o += 128) {
    int n = o / TT, f = o - n*TT;
    float a0 = 0.f, a1 = 0.f;
    for (int t = 0; t < TT; t += 2) {
      a0 += s_xs[n*TT + t    ] * s_Mt[(t    )*TT + f];
      a1 += s_xs[n*TT + t + 1] * s_Mt[(t + 1)*TT + f];
    }
    s_tp[o] = a0 + a1;
  }
  __syncthreads();

  for (int o = tid; o < CC*TT; o += 128) {
    int c = o / TT, t = o - c*TT;
    s_comb[c*CPAD + t] = st_bo[c] + ts_bo[t];
  }

  {
    float* s_k = s_kv;
    float* s_v = s_kv + TT*HD;
    for (int h = 0; h < HH; ++h) {
      const int base = h*HD;
      __syncthreads();
      {
        const int d = tid & 63, krow = tid >> 6;
        for (int kk = 0; kk < CC/2; ++kk) {
          int k = kk*2 + krow;
          float aK = st_bk[base + d], aV = st_bv[base + d];
          const float* tr = s_tp + k*TT;
          for (int t = 0; t < TT; ++t) {
            float a = tr[t];
            aK += a * st_wk[(long)t*EE + base + d];
            aV += a * st_wv[(long)t*EE + base + d];
          }
          s_k[k*HD + d] = aK;
          s_v[k*HD + d] = aV;
        }
      }
      __syncthreads();
      if (tid < TT) {
        const int q = tid;
        float qv[HD];
        #pragma unroll
        for (int d = 0; d < HD; ++d) qv[d] = st_bq[base + d];
        for (int c = 0; c < CC; ++c) {
          float a = s_sp[c*TT + q];
          const float* wr = st_wq + (long)c*EE + base;
          #pragma unroll
          for (int d = 0; d < HD; ++d) qv[d] += a * wr[d];
        }
        float m = -INFINITY, l = 0.f, ov[HD];
        #pragma unroll
        for (int d = 0; d < HD; ++d) ov[d] = 0.f;
        for (int k = 0; k < CC; ++k) {
          const float4* kr4 = (const float4*)(s_k + k*HD);
          float s0=0.f,s1=0.f,s2=0.f,s3=0.f;
          #pragma unroll
          for (int i = 0; i < 16; ++i) {
            float4 kk4 = kr4[i];
            s0 += qv[4*i  ]*kk4.x; s1 += qv[4*i+1]*kk4.y;
            s2 += qv[4*i+2]*kk4.z; s3 += qv[4*i+3]*kk4.w;
          }
          float s  = (s0+s1+s2+s3) * 0.125f;
          float mn = fmaxf(m, s);
          float corr = __expf(m - mn);
          float p    = __expf(s - mn);
          l = l*corr + p;
          const float4* vr4 = (const float4*)(s_v + k*HD);
          #pragma unroll
          for (int i = 0; i < 16; ++i) {
            float4 vv4 = vr4[i];
            ov[4*i  ] = ov[4*i  ]*corr + p*vv4.x;
            ov[4*i+1] = ov[4*i+1]*corr + p*vv4.y;
            ov[4*i+2] = ov[4*i+2]*corr + p*vv4.z;
            ov[4*i+3] = ov[4*i+3]*corr + p*vv4.w;
          }
          m = mn;
        }
        float rl = 1.f/l;
        #pragma unroll
        for (int d = 0; d < HD; ++d) ov[d] *= rl;
        for (int c = 0; c < CC; ++c) {
          const float* wr = st_wo + (long)base*CC + c;
          float a0=0.f,a1=0.f,a2=0.f,a3=0.f;
          #pragma unroll
          for (int d = 0; d < HD; d += 4) {
            a0 += ov[d  ]*wr[(long)(d  )*CC]; a1 += ov[d+1]*wr[(long)(d+1)*CC];
            a2 += ov[d+2]*wr[(long)(d+2)*CC]; a3 += ov[d+3]*wr[(long)(d+3)*CC];
          }
          s_comb[c*CPAD + q] += a0+a1+a2+a3;
        }
      }
    }
  }

  {
    float* s_k = s_kv;
    float* s_v = s_kv + TT*HD;
    for (int h = 0; h < HH; ++h) {
      const int base = h*HD;
      __syncthreads();
      {
        const int d = tid & 63, krow = tid >> 6;
        for (int kk = 0; kk < TT/2; ++kk) {
          int k = kk*2 + krow;
          float aK = ts_bk[base + d], aV = ts_bv[base + d];
          for (int c = 0; c < CC; ++c) {
            float a = s_sp[c*TT + k];
            aK += a * ts_wk[(long)c*EE + base + d];
            aV += a * ts_wv[(long)c*EE + base + d];
          }
          s_k[k*HD + d] = aK;
          s_v[k*HD + d] = aV;
        }
      }
      __syncthreads();
      if (tid < CC) {
        const int q = tid;
        float qv[HD];
        #pragma unroll
        for (int d = 0; d < HD; ++d) qv[d] = ts_bq[base + d];
        const float* tr = s_tp + q*TT;
        for (int t = 0; t < TT; ++t) {
          float a = tr[t];
          const float* wr = ts_wq + (long)t*EE + base;
          #pragma unroll
          for (int d = 0; d < HD; ++d) qv[d] += a * wr[d];
        }
        float m = -INFINITY, l = 0.f, ov[HD];
        #pragma unroll
        for (int d = 0; d < HD; ++d) ov[d] = 0.f;
        for (int k = 0; k < TT; ++k) {
          const float4* kr4 = (const float4*)(s_k + k*HD);
          float s0=0.f,s1=0.f,s2=0.f,s3=0.f;
          #pragma unroll
          for (int i = 0; i < 16; ++i) {
            float4 kk4 = kr4[i];
            s0 += qv[4*i  ]*kk4.x; s1 += qv[4*i+1]*kk4.y;
            s2 += qv[4*i+2]*kk4.z; s3 += qv[4*i+3]*kk4.w;
          }
          float s  = (s0+s1+s2+s3) * 0.125f;
          float mn = fmaxf(m, s);
          float corr = __expf(m - mn);
          float p    = __expf(s - mn);
          l = l*corr + p;
          const float4* vr4 = (const float4*)(s_v + k*HD);
          #pragma unroll
          for (int i = 0; i < 16; ++i) {
            float4 vv4 = vr4[i];
            ov[4*i  ] = ov[4*i  ]*corr + p*vv4.x;
            ov[4*i+1] = ov[4*i+1]*corr + p*vv4.y;
            ov[4*i+2] = ov[4*i+2]*corr + p*vv4.z;
            ov[4*i+3] = ov[4*i+3]*corr + p*vv4.w;
          }
          m = mn;
        }
        float rl = 1.f/l;
        #pragma unroll
        for (int d = 0; d < HD; ++d) ov[d] *= rl;
        for (int t = 0; t < TT; ++t) {
          const float* wr = ts_wo + (long)base*TT + t;
          float a0=0.f,a1=0.f,a2=0.f,a3=0.f;
          #pragma unroll
          for (int d = 0; d < HD; d += 4) {
            a0 += ov[d  ]*wr[(long)(d  )*TT]; a1 += ov[d+1]*wr[(long)(d+1)*TT];
            a2 += ov[d+2]*wr[(long)(d+2)*TT]; a3 += ov[d+3]*wr[(long)(d+3)*TT];
          }
          s_comb[q*CPAD + t] += a0+a1+a2+a3;
        }
      }
    }
  }
  __syncthreads();

  if (tid < TT) {
    const int t = tid;
    float mean = 0.f;
    for (int c = 0; c < CC; ++c) mean += s_comb[c*CPAD + t];
    mean *= (1.f/CC);
    float var = 0.f;
    for (int c = 0; c < CC; ++c) { float dv = s_comb[c*CPAD + t] - mean; var += dv*dv; }
    var *= (1.f/CC);
    float rstd = 1.f / sqrtf(var + 1e-5f);
    for (int c = 0; c < CC; ++c) {
      float y = (s_comb[c*CPAD + t] - mean) * rstd * alpha[c] + beta[c];
      s_comb[c*CPAD + t] = y + x[bb + c*TT + t];
    }
  }
  __syncthreads();

  float* s_w = s_kv;
  for (int o = tid; o < TT*TT; o += 128) {
    int f = o / TT, t = o - f*TT;
    s_w[t*TT + f] = fcw[o];
  }
  __syncthreads();

  for (int o = tid; o < CC*TT; o += 128) {
    int c = o / TT, f = o - c*TT;
    const float* cr = s_comb + c*CPAD;
    float a0 = 0.f, a1 = 0.f;
    for (int t = 0; t < TT; t += 2) {
      a0 += cr[t    ] * s_w[(t    )*TT + f];
      a1 += cr[t + 1] * s_w[(t + 1)*TT + f];
    }
    out[bb + o] = tanhf(a0 + a1 + fcb[f]);
  }
}

// ---------------------------------------------------------------- launch
extern "C" void kernel_launch(void* const* d_in, const int* in_sizes, int n_in,
                              void* d_out, int out_size, void* d_ws, size_t ws_size,
                              hipStream_t stream) {
  const float* x     = (const float*)d_in[0];
  const float* adj   = (const float*)d_in[1];
  const float* sadj  = (const float*)d_in[2];
  const float* tmask = (const float*)d_in[3];
  const float* tadj  = (const float*)d_in[4];
  const float* st_wq = (const float*)d_in[5];  const float* st_bq = (const float*)d_in[6];
  const float* st_wk = (const float*)d_in[7];  const float* st_bk = (const float*)d_in[8];
  const float* st_wv = (const float*)d_in[9];  const float* st_bv = (const float*)d_in[10];
  const float* st_wo = (const float*)d_in[11]; const float* st_bo = (const float*)d_in[12];
  const float* ts_wq = (const float*)d_in[13]; const float* ts_bq = (const float*)d_in[14];
  const float* ts_wk = (const float*)d_in[15]; const float* ts_bk = (const float*)d_in[16];
  const float* ts_wv = (const float*)d_in[17]; const float* ts_bv = (const float*)d_in[18];
  const float* ts_wo = (const float*)d_in[19]; const float* ts_bo = (const float*)d_in[20];
  const float* alpha = (const float*)d_in[21]; const float* beta  = (const float*)d_in[22];
  const float* fcw   = (const float*)d_in[23]; const float* fcb   = (const float*)d_in[24];
  float* out = (float*)d_out;

  const int B = in_sizes[0] / (CC*TT);
  const size_t comb_bytes = (size_t)B * CC * TT * 4;
  const size_t w_bytes    = (size_t)W_TOTAL * 2;
  const size_t spt_bytes  = (size_t)B * SPT_R * SPT_S * 2;
  const size_t tp_bytes   = (size_t)B * TP_R * TP_S * 2;
  const size_t need_plain  = 2*comb_bytes + w_bytes + spt_bytes + tp_bytes;
  const size_t need_atomic =   comb_bytes + w_bytes + spt_bytes + tp_bytes;

  if (ws_size >= need_atomic) {
    const int plain = (ws_size >= need_plain) ? 1 : 0;
    const size_t cbuf = plain ? 2*comb_bytes : comb_bytes;
    float* c1      = (float*)d_ws;                       // plain: [B][T][C]; atomic: comb
    float* c2      = plain ? (float*)((char*)d_ws + comb_bytes) : nullptr;  // [B][C][T]
    bf16*  wsec    = (bf16*)((char*)d_ws + cbuf);
    bf16*  spT_all = (bf16*)((char*)d_ws + cbuf + w_bytes);
    bf16*  tp_all  = spT_all + (size_t)B * SPT_R * SPT_S;

    if (!plain) hipMemsetAsync(c1, 0, comb_bytes, stream);
    // weight pre-transposes (one-off, tiny)
    k_tr<<<(512*128+255)/256, 256, 0, stream>>>(st_wk, wsec + W_STWK, TT, EE, EE, 128);
    k_tr<<<(512*128+255)/256, 256, 0, stream>>>(st_wv, wsec + W_STWV, TT, EE, EE, 128);
    k_tr<<<(512* 96+255)/256, 256, 0, stream>>>(st_wq, wsec + W_STWQ, CC, EE, EE,  96);
    k_tr<<<( 80*512+255)/256, 256, 0, stream>>>(st_wo, wsec + W_STWO, EE, CC,  80, 512);
    k_tr<<<(512* 96+255)/256, 256, 0, stream>>>(ts_wk, wsec + W_TSWK, CC, EE, EE,  96);
    k_tr<<<(512* 96+255)/256, 256, 0, stream>>>(ts_wv, wsec + W_TSWV, CC, EE, EE,  96);
    k_tr<<<(512*128+255)/256, 256, 0, stream>>>(ts_wq, wsec + W_TSWQ, TT, EE, EE, 128);
    k_tr<<<(112*512+255)/256, 256, 0, stream>>>(ts_wo, wsec + W_TSWO, EE, TT, 112, 512);

    k_prep<<<B, 256, 0, stream>>>(x, adj, sadj, tmask, tadj, spT_all, tp_all);
    k_attn<<<B*2, 512, 0, stream>>>(spT_all, tp_all, wsec,
                                    st_bq, st_bv, ts_bq, ts_bv,
                                    plain ? c1 : nullptr, c2,
                                    plain ? nullptr : c1, plain);
    k_epi<<<B, 256, 0, stream>>>(plain ? nullptr : c1, c1, c2, x,
                                 st_bo, ts_bo, alpha, beta, fcw, fcb, out, plain);
  } else {
    k_fused<<<B, 128, 0, stream>>>(x, adj, sadj, tmask, tadj,
                                   st_wq, st_bq, st_wk, st_bk, st_wv, st_bv, st_wo, st_bo,
                                   ts_wq, ts_bq, ts_wk, ts_bk, ts_wv, ts_bv, ts_wo, ts_bo,
                                   alpha, beta, fcw, fcb, out);
  }
}

// Round 3
// 1102.845 us; speedup vs baseline: 1.9399x; 1.9399x over previous
//
#include <hip/hip_runtime.h>
#include <hip/hip_bf16.h>
#include <math.h>
#include <stdint.h>

typedef __hip_bfloat16 bf16;
typedef __attribute__((ext_vector_type(8))) short short8;
typedef __attribute__((ext_vector_type(4))) short short4v;
typedef __attribute__((ext_vector_type(4))) float f32x4;

#define CC 66      // channels = J*DIMS
#define TT 100     // time steps
#define JJ 22      // joints
#define HH 8       // heads
#define HD 64      // head dim
#define EE 512     // embed
#define CPAD 101   // comb LDS stride in k_epi / k_fused

// padded token layouts in ws (zero-padded so MFMA K-chunks read clean zeros)
#define SPT_R 112  // spT rows (>=100, mult of 16)
#define SPT_S 96   // spT stride (>=66, mult of 32 for k-chunks)
#define TP_R 80    // tp rows (>=66)
#define TP_S 128   // tp stride (>=100)

// weight section offsets (bf16 elements) inside ws
#define W_STWK 0                    // [512][128]
#define W_STWV 65536                // [512][128]
#define W_STWQ 131072               // [512][96]
#define W_STWO 180224               // [80][512]
#define W_TSWK 221184               // [512][96]
#define W_TSWV 270336               // [512][96]
#define W_TSWQ 319488               // [512][128]
#define W_TSWO 385024               // [112][512]
#define W_TOTAL 442368

__device__ __forceinline__ float b2f(bf16 v){ return __bfloat162float(v); }
__device__ __forceinline__ bf16 f2b(float v){ return __float2bfloat16(v); }
__device__ __forceinline__ short sb(float v){ __hip_bfloat16 h = __float2bfloat16(v); return *(short*)&h; }
__device__ __forceinline__ float fb(short s){ __hip_bfloat16 h; *(short*)&h = s; return __bfloat162float(h); }

// ---------------------------------------------------------------- k_tr
__global__ void k_tr(const float* __restrict__ src, bf16* __restrict__ dst,
                     int Rsrc, int Csrc, int JP, int IP)
{
  int o = blockIdx.x*256 + threadIdx.x;
  if (o >= JP*IP) return;
  int j = o / IP, i = o - j*IP;
  float v = (j < Csrc && i < Rsrc) ? src[(long)i*Csrc + j] : 0.f;
  dst[o] = f2b(v);
}

// ---------------------------------------------------------------- k_prep
__global__ __launch_bounds__(256) void k_prep(
    const float* __restrict__ x, const float* __restrict__ adj,
    const float* __restrict__ sadj, const float* __restrict__ tmask,
    const float* __restrict__ tadj,
    bf16* __restrict__ spT_all, bf16* __restrict__ tp_all)
{
  __shared__ float s_x[CC*TT];
  __shared__ float s_Mt[TT*TT];
  __shared__ float s_A[JJ*JJ];
  __shared__ float s_dis[JJ];
  const int b = blockIdx.x, tid = threadIdx.x;
  const long bb = (long)b * (CC*TT);

  if (tid < JJ) {
    float dsum = 0.f;
    for (int i = 0; i < JJ; ++i) dsum += adj[tid*JJ + i];
    s_dis[tid] = dsum > 0.f ? rsqrtf(dsum) : 0.f;
  }
  for (int o = tid; o < CC*TT; o += 256) s_x[o] = x[bb + o];
  for (int o = tid; o < TT*TT; o += 256) {
    int f = o / TT, t = o - f*TT;
    s_Mt[t*TT + f] = tadj[o] * tmask[o];
  }
  __syncthreads();
  for (int o = tid; o < JJ*JJ; o += 256) {
    int v = o / JJ, j = o - v*JJ;
    s_A[o] = sadj[o] * adj[o] * s_dis[v] * s_dis[j];
  }
  __syncthreads();

  bf16* spT = spT_all + (long)b * (SPT_R*SPT_S);
  bf16* tp  = tp_all  + (long)b * (TP_R*TP_S);

  for (int o = tid; o < SPT_R*SPT_S; o += 256) {
    int t = o / SPT_S, c = o - t*SPT_S;
    float acc = 0.f;
    if (t < TT && c < CC) {
      int v = c / 3, dd = c - v*3;
      for (int j = 0; j < JJ; ++j) acc += s_A[v*JJ + j] * s_x[(j*3 + dd)*TT + t];
    }
    spT[o] = f2b(acc);
  }
  for (int o = tid; o < TP_R*TP_S; o += 256) {
    int n = o / TP_S, f = o - n*TP_S;
    float acc = 0.f;
    if (n < CC && f < TT) {
      float a0 = 0.f, a1 = 0.f;
      for (int t = 0; t < TT; t += 2) {
        a0 += s_x[n*TT + t    ] * s_Mt[(t    )*TT + f];
        a1 += s_x[n*TT + t + 1] * s_Mt[(t + 1)*TT + f];
      }
      acc = a0 + a1;
    }
    tp[o] = f2b(acc);
  }
}

// ---------------------------------------------------------------- MFMA helper
// Compile-time tile counts, strides and swizzle flags.
// A[m=lane&15][k=quad*8+j]; B[n=lane&15][k=quad*8+j]; D col=lane&15,row=quad*4+reg.
// Swizzled arrays use logical stride with col XOR ((row&7)<<3) at 8-short
// granularity (keeps 16B alignment; 2-way bank spread on b128 reads).
template<int Mt, int Nt, int KCH, int SA, int SB, int SD, bool SWA, bool SWB, bool SWD>
__device__ __forceinline__ void mm_tiles_t(
    const short* __restrict__ Am, const short* __restrict__ Bm,
    short* __restrict__ D, const float* __restrict__ bias, float scale,
    int wave, int ln, int qd)
{
  constexpr int NTILE = Mt*Nt;
  constexpr int NU = (NTILE + 7) / 8;
  #pragma unroll
  for (int u = 0; u < NU; ++u) {
    int ti = u*8 + wave;
    if (ti < NTILE) {
      int mi = ti / Nt, ni = ti - mi*Nt;
      f32x4 acc = {0.f, 0.f, 0.f, 0.f};
      const int ar = mi*16 + ln, br = ni*16 + ln;
      const int sza = SWA ? ((ar&7)<<3) : 0;
      const int szb = SWB ? ((br&7)<<3) : 0;
      const short* ap = Am + (long)ar*SA;
      const short* bp = Bm + (long)br*SB;
      #pragma unroll
      for (int kc = 0; kc < KCH; ++kc) {
        short8 af = *(const short8*)(ap + ((qd*8 + kc*32) ^ sza));
        short8 bf = *(const short8*)(bp + ((qd*8 + kc*32) ^ szb));
        acc = __builtin_amdgcn_mfma_f32_16x16x32_bf16(af, bf, acc, 0, 0, 0);
      }
      int col = ni*16 + ln;
      float bv_ = bias ? bias[col] : 0.f;
      #pragma unroll
      for (int r = 0; r < 4; ++r) {
        int row = mi*16 + qd*4 + r;
        int cs = SWD ? (col ^ ((row&7)<<3)) : col;
        D[row*SD + cs] = sb((acc[r] + bv_) * scale);
      }
    }
  }
}

// ---------------------------------------------------------------- attn body
// A=0: q = spatial tokens (100), kv = temporal (66)
// A=1: q = temporal tokens (66), kv = spatial (100)
// Per head: ONE cooperative build phase (K->Z1, Q->Z2, VT->Z3; 2 barriers),
// then each wave owns q-tile mi=wave and runs S -> in-register softmax ->
// P store -> PV -> O store -> Oproj with NO barriers (wave-local lgkmcnt only).
template<int A>
__device__ __forceinline__ void attn_body(
    short* __restrict__ SMEM,
    const bf16* __restrict__ spT_all, const bf16* __restrict__ tp_all,
    const bf16* __restrict__ wsec,
    const float* __restrict__ st_bq, const float* __restrict__ st_bv,
    const float* __restrict__ ts_bq, const float* __restrict__ ts_bv,
    float* __restrict__ o1, float* __restrict__ o2, float* __restrict__ comb_g,
    int plain)
{
  constexpr int QROWS = A ? 66 : 100;
  constexpr int KROWS = A ? 100 : 66;
  constexpr int MQ  = A ? 5 : 7;     // q-tiles (16 rows each)
  constexpr int MK  = A ? 7 : 5;     // kv-tiles
  constexpr int QCH = A ? 4 : 3;     // q-projection k-chunks
  constexpr int KCH = A ? 3 : 4;     // k/v-projection k-chunks
  constexpr int PCH = A ? 4 : 3;     // PV k-chunks (over kv dim)
  constexpr int SAQ = A ? TP_S : SPT_S;
  constexpr int SAK = A ? SPT_S : TP_S;
  constexpr int KRP = MK*16;         // K rows padded (80 / 112)
  constexpr int QRP = MQ*16;         // Q rows padded (112 / 80)
  constexpr int VTS = A ? 136 : 104; // VT stride (non-pow2 -> no swizzle needed)
  constexpr int PS  = A ? 136 : 104; // Pm stride

  // zone carve: A=0 30,592 shorts; A=1 31,872 shorts
  short* Z1 = SMEM;                  // K  [KRP][64]  swizzled
  short* Z2 = Z1 + KRP*64;           // Q  [QRP][64]  swizzled
  short* Z3 = Z2 + QRP*64;           // VT [64][VTS]  plain
  short* Pm = Z3 + 64*VTS;           // P then O per wave-row-block [QRP][PS]

  const int b = blockIdx.x >> 1, tid = threadIdx.x;
  const long bb = (long)b * (CC*TT);
  const int wave = tid >> 6, lane = tid & 63, ln = lane & 15, qd = lane >> 4;

  const short* Aq = (const short*)(A ? (tp_all  + (long)b*TP_R*TP_S)
                                     : (spT_all + (long)b*SPT_R*SPT_S));
  const short* Ak = (const short*)(A ? (spT_all + (long)b*SPT_R*SPT_S)
                                     : (tp_all  + (long)b*TP_R*TP_S));
  const short* wqT = (const short*)(wsec + (A ? W_TSWQ : W_STWQ));
  const short* wkT = (const short*)(wsec + (A ? W_TSWK : W_STWK));
  const short* wvT = (const short*)(wsec + (A ? W_TSWV : W_STWV));
  const short* woT = (const short*)(wsec + (A ? W_TSWO : W_STWO));
  const float* bq = A ? ts_bq : st_bq;
  const float* bv = A ? ts_bv : st_bv;

  // one-time zero: all of Pm (pad cols must stay 0 for PV k-chunk reads) and
  // VT pad cols [MK*16, MK*16+16) (never written by builds, read by PV).
  for (int o = tid; o < QRP*PS; o += 512) Pm[o] = 0;
  for (int o = tid; o < 64*16; o += 512) {
    int d = o >> 4, c = MK*16 + (o & 15);
    Z3[d*VTS + c] = 0;
  }

  f32x4 accO[MK];
  { f32x4 z = {0.f,0.f,0.f,0.f};
    #pragma unroll
    for (int i = 0; i < MK; ++i) accO[i] = z; }

  for (int h = 0; h < HH; ++h) {
    const int base = h*HD;
    __syncthreads();   // Z1/Z2/Z3 free of prev head's readers (h=0: inits done)
    // cooperative builds (disjoint outputs, global operands)
    mm_tiles_t<MK,4,KCH, SAK,SAK,64, false,false,true>(
        Ak, wkT + (long)base*SAK, Z1, nullptr, 1.f, wave, ln, qd);      // K
    mm_tiles_t<MQ,4,QCH, SAQ,SAQ,64, false,false,true>(
        Aq, wqT + (long)base*SAQ, Z2, bq + base, 1.f, wave, ln, qd);    // Q
    mm_tiles_t<4,MK,KCH, SAK,SAK,VTS, false,false,false>(
        wvT + (long)base*SAK, Ak, Z3, nullptr, 1.f, wave, ln, qd);      // V^T
    __syncthreads();

    if (wave < MQ) {
      const int mi = wave;
      // ---- S = Q @ K^T (all MK n-tiles in registers) ----
      f32x4 s[MK];
      const int ar = mi*16 + ln;
      const int sza = (ar&7)<<3;
      const short* ap = Z2 + ar*64;
      #pragma unroll
      for (int ni = 0; ni < MK; ++ni) {
        const int br = ni*16 + ln;
        const int szb = (br&7)<<3;
        const short* bp = Z1 + br*64;
        f32x4 acc = {0.f,0.f,0.f,0.f};
        #pragma unroll
        for (int kc = 0; kc < 2; ++kc) {
          acc = __builtin_amdgcn_mfma_f32_16x16x32_bf16(
              *(const short8*)(ap + ((qd*8 + kc*32) ^ sza)),
              *(const short8*)(bp + ((qd*8 + kc*32) ^ szb)), acc, 0,0,0);
        }
        s[ni] = acc;
      }
      // ---- in-register softmax (rows = mi*16+qd*4+r; cols spread over
      //      16 lanes x MK regs; reduce via shfl_xor within 16-lane group) ----
      #pragma unroll
      for (int ni = 0; ni < MK; ++ni) {
        bool bad = (ni*16 + ln) >= KROWS;   // K pad cols -> mask to -inf
        #pragma unroll
        for (int r = 0; r < 4; ++r) s[ni][r] = bad ? -1e30f : s[ni][r]*0.125f;
      }
      #pragma unroll
      for (int r = 0; r < 4; ++r) {
        float m = -1e30f;
        #pragma unroll
        for (int ni = 0; ni < MK; ++ni) m = fmaxf(m, s[ni][r]);
        m = fmaxf(m, __shfl_xor(m, 1));
        m = fmaxf(m, __shfl_xor(m, 2));
        m = fmaxf(m, __shfl_xor(m, 4));
        m = fmaxf(m, __shfl_xor(m, 8));
        float l = 0.f;
        #pragma unroll
        for (int ni = 0; ni < MK; ++ni) {
          float p = __expf(s[ni][r] - m);   // masked cols: exp(-huge)=0
          s[ni][r] = p;
          l += p;
        }
        l += __shfl_xor(l, 1);
        l += __shfl_xor(l, 2);
        l += __shfl_xor(l, 4);
        l += __shfl_xor(l, 8);
        float rs = 1.f / l;
        #pragma unroll
        for (int ni = 0; ni < MK; ++ni) s[ni][r] *= rs;
      }
      // ---- store P (bf16) to own row block; pad cols stay 0 ----
      short* prow = Pm + (mi*16)*PS;
      #pragma unroll
      for (int ni = 0; ni < MK; ++ni) {
        #pragma unroll
        for (int r = 0; r < 4; ++r)
          prow[(qd*4 + r)*PS + ni*16 + ln] = sb(s[ni][r]);
      }
      // ---- PV: O = P @ V (wave-local LDS ordering; no barrier) ----
      const short* pap = Pm + (mi*16 + ln)*PS;
      f32x4 ot[4];
      #pragma unroll
      for (int di = 0; di < 4; ++di) {
        const short* bp = Z3 + (di*16 + ln)*VTS;
        f32x4 acc = {0.f,0.f,0.f,0.f};
        #pragma unroll
        for (int kc = 0; kc < PCH; ++kc) {
          acc = __builtin_amdgcn_mfma_f32_16x16x32_bf16(
              *(const short8*)(pap + qd*8 + kc*32),
              *(const short8*)(bp  + qd*8 + kc*32), acc, 0,0,0);
        }
        ot[di] = acc;
      }
      // ---- O (+bv) -> own row block cols 0..63 (P dead for this wave) ----
      #pragma unroll
      for (int di = 0; di < 4; ++di) {
        float bvv = bv[base + di*16 + ln];
        #pragma unroll
        for (int r = 0; r < 4; ++r)
          prow[(qd*4 + r)*PS + di*16 + ln] = sb(ot[di][r] + bvv);
      }
      // ---- Oproj: accO[ni] += O @ woT (B from global) ----
      #pragma unroll
      for (int ni = 0; ni < MK; ++ni) {
        const short* bp = woT + (long)(ni*16 + ln)*512 + base;
        f32x4 acc = accO[ni];
        acc = __builtin_amdgcn_mfma_f32_16x16x32_bf16(
            *(const short8*)(pap + qd*8),
            *(const short8*)(bp + qd*8), acc, 0,0,0);
        acc = __builtin_amdgcn_mfma_f32_16x16x32_bf16(
            *(const short8*)(pap + qd*8 + 32),
            *(const short8*)(bp + qd*8 + 32), acc, 0,0,0);
        accO[ni] = acc;
      }
    }
  }

  // accumulated out-proj -> per-flavor buffer (plain) or comb (atomic)
  if (wave < MQ) {
    const int mi = wave;
    #pragma unroll
    for (int ni = 0; ni < MK; ++ni) {
      int col = ni*16 + ln;
      #pragma unroll
      for (int r = 0; r < 4; ++r) {
        int row = mi*16 + qd*4 + r;
        if (row < QROWS && col < KROWS) {
          if (plain) {
            if (A) o2[bb + (long)row*TT + col] = accO[ni][r];   // [c][t]
            else   o1[bb + (long)row*CC + col] = accO[ni][r];   // [t][c]
          } else {
            long off = A ? ((long)row*TT + col) : ((long)col*TT + row);
            atomicAdd(&comb_g[bb + off], accO[ni][r]);
          }
        }
      }
    }
  }
}

// ---------------------------------------------------------------- k_attn
// LDS 63,744 B -> 2 blocks/CU; natural VGPR (NO min-occupancy cap: round-2's
// (512,6) forced 40 VGPR and 4 GB of scratch spill traffic).
__global__ __launch_bounds__(512) void k_attn(
    const bf16* __restrict__ spT_all, const bf16* __restrict__ tp_all,
    const bf16* __restrict__ wsec,
    const float* __restrict__ st_bq, const float* __restrict__ st_bv,
    const float* __restrict__ ts_bq, const float* __restrict__ ts_bv,
    float* __restrict__ o1, float* __restrict__ o2,
    float* __restrict__ comb_g, int plain)
{
  __shared__ __align__(16) short SMEM[31872];
  if (blockIdx.x & 1)
    attn_body<1>(SMEM,spT_all,tp_all,wsec,st_bq,st_bv,ts_bq,ts_bv,o1,o2,comb_g,plain);
  else
    attn_body<0>(SMEM,spT_all,tp_all,wsec,st_bq,st_bv,ts_bq,ts_bv,o1,o2,comb_g,plain);
}

// ---------------------------------------------------------------- k_epi
__global__ __launch_bounds__(256) void k_epi(
    const float* __restrict__ comb_g,
    const float* __restrict__ c1, const float* __restrict__ c2,
    const float* __restrict__ x,
    const float* __restrict__ st_bo, const float* __restrict__ ts_bo,
    const float* __restrict__ alpha, const float* __restrict__ beta,
    const float* __restrict__ fcw, const float* __restrict__ fcb,
    float* __restrict__ out, int plain)
{
  __shared__ float s_cb[CC*CPAD];
  __shared__ float s_w[TT*TT];
  const int b = blockIdx.x, tid = threadIdx.x;
  const long bb = (long)b * (CC*TT);

  for (int o = tid; o < CC*TT; o += 256) {
    int c = o / TT, t = o - c*TT;
    float v;
    if (plain) v = c1[bb + (long)t*CC + c] + c2[bb + o];
    else       v = comb_g[bb + o];
    s_cb[c*CPAD + t] = v + st_bo[c] + ts_bo[t];
  }
  for (int o = tid; o < TT*TT; o += 256) {
    int f = o / TT, t = o - f*TT;
    s_w[t*TT + f] = fcw[o];
  }
  __syncthreads();
  // LN over channels: 2 lanes per t-column (200 threads), shfl_xor combine
  if (tid < 2*TT) {
    const int t = tid >> 1, hf = tid & 1;
    float part = 0.f;
    for (int c = hf; c < CC; c += 2) part += s_cb[c*CPAD + t];
    float mean = (part + __shfl_xor(part, 1)) * (1.f/CC);
    float vp = 0.f;
    for (int c = hf; c < CC; c += 2) { float dv = s_cb[c*CPAD + t] - mean; vp += dv*dv; }
    float var = (vp + __shfl_xor(vp, 1)) * (1.f/CC);
    float rstd = 1.f / sqrtf(var + 1e-5f);
    for (int c = hf; c < CC; c += 2) {
      float y = (s_cb[c*CPAD + t] - mean) * rstd * alpha[c] + beta[c];
      s_cb[c*CPAD + t] = y + x[bb + c*TT + t];
    }
  }
  __syncthreads();
  for (int o = tid; o < CC*TT; o += 256) {
    int c = o / TT, f = o - c*TT;
    const float* cr = s_cb + c*CPAD;
    float a0 = 0.f, a1 = 0.f;
    for (int t = 0; t < TT; t += 2) {
      a0 += cr[t    ] * s_w[(t    )*TT + f];
      a1 += cr[t + 1] * s_w[(t + 1)*TT + f];
    }
    out[bb + o] = tanhf(a0 + a1 + fcb[f]);
  }
}

// ---------------------------------------------------------------- R4 fallback
__global__ __launch_bounds__(128) void k_fused(
    const float* __restrict__ x, const float* __restrict__ adj,
    const float* __restrict__ sadj, const float* __restrict__ tmask,
    const float* __restrict__ tadj,
    const float* __restrict__ st_wq, const float* __restrict__ st_bq,
    const float* __restrict__ st_wk, const float* __restrict__ st_bk,
    const float* __restrict__ st_wv, const float* __restrict__ st_bv,
    const float* __restrict__ st_wo, const float* __restrict__ st_bo,
    const float* __restrict__ ts_wq, const float* __restrict__ ts_bq,
    const float* __restrict__ ts_wk, const float* __restrict__ ts_bk,
    const float* __restrict__ ts_wv, const float* __restrict__ ts_bv,
    const float* __restrict__ ts_wo, const float* __restrict__ ts_bo,
    const float* __restrict__ alpha, const float* __restrict__ beta,
    const float* __restrict__ fcw, const float* __restrict__ fcb,
    float* __restrict__ out)
{
  __shared__ float s_sp[CC*TT];
  __shared__ float s_tp[CC*TT];
  __shared__ __align__(16) float s_kv[2*TT*HD];
  __shared__ float s_comb[CC*CPAD];
  __shared__ float s_A[JJ*JJ];
  __shared__ float s_dis[JJ];

  const int b = blockIdx.x, tid = threadIdx.x;
  const long bb = (long)b * (CC*TT);
  float* s_xs = s_comb;
  float* s_Mt = s_kv;

  if (tid < JJ) {
    float dsum = 0.f;
    for (int i = 0; i < JJ; ++i) dsum += adj[tid*JJ + i];
    s_dis[tid] = dsum > 0.f ? rsqrtf(dsum) : 0.f;
  }
  for (int o = tid; o < CC*TT; o += 128) s_xs[o] = x[bb + o];
  for (int o = tid; o < TT*TT; o += 128) {
    int f = o / TT, t = o - f*TT;
    s_Mt[t*TT + f] = tadj[o] * tmask[o];
  }
  __syncthreads();
  for (int o = tid; o < JJ*JJ; o += 128) {
    int v = o / JJ, j = o - v*JJ;
    s_A[o] = sadj[o] * adj[o] * s_dis[v] * s_dis[j];
  }
  __syncthreads();

  for (int o = tid; o < CC*TT; o += 128) {
    int c = o / TT, t = o - c*TT, v = c / 3, dd = c - v*3;
    float acc = 0.f;
    for (int j = 0; j < JJ; ++j) acc += s_A[v*JJ + j] * s_xs[(j*3 + dd)*TT + t];
    s_sp[o] = acc;
  }
  for (int o = tid; o < CC*TT; o += 128) {
    int n = o / TT, f = o - n*TT;
    float a0 = 0.f, a1 = 0.f;
    for (int t = 0; t < TT; t += 2) {
      a0 += s_xs[n*TT + t    ] * s_Mt[(t    )*TT + f];
      a1 += s_xs[n*TT + t + 1] * s_Mt[(t + 1)*TT + f];
    }
    s_tp[o] = a0 + a1;
  }
  __syncthreads();

  for (int o = tid; o < CC*TT; o += 128) {
    int c = o / TT, t = o - c*TT;
    s_comb[c*CPAD + t] = st_bo[c] + ts_bo[t];
  }

  {
    float* s_k = s_kv;
    float* s_v = s_kv + TT*HD;
    for (int h = 0; h < HH; ++h) {
      const int base = h*HD;
      __syncthreads();
      {
        const int d = tid & 63, krow = tid >> 6;
        for (int kk = 0; kk < CC/2; ++kk) {
          int k = kk*2 + krow;
          float aK = st_bk[base + d], aV = st_bv[base + d];
          const float* tr = s_tp + k*TT;
          for (int t = 0; t < TT; ++t) {
            float a = tr[t];
            aK += a * st_wk[(long)t*EE + base + d];
            aV += a * st_wv[(long)t*EE + base + d];
          }
          s_k[k*HD + d] = aK;
          s_v[k*HD + d] = aV;
        }
      }
      __syncthreads();
      if (tid < TT) {
        const int q = tid;
        float qv[HD];
        #pragma unroll
        for (int d = 0; d < HD; ++d) qv[d] = st_bq[base + d];
        for (int c = 0; c < CC; ++c) {
          float a = s_sp[c*TT + q];
          const float* wr = st_wq + (long)c*EE + base;
          #pragma unroll
          for (int d = 0; d < HD; ++d) qv[d] += a * wr[d];
        }
        float m = -INFINITY, l = 0.f, ov[HD];
        #pragma unroll
        for (int d = 0; d < HD; ++d) ov[d] = 0.f;
        for (int k = 0; k < CC; ++k) {
          const float4* kr4 = (const float4*)(s_k + k*HD);
          float s0=0.f,s1=0.f,s2=0.f,s3=0.f;
          #pragma unroll
          for (int i = 0; i < 16; ++i) {
            float4 kk4 = kr4[i];
            s0 += qv[4*i  ]*kk4.x; s1 += qv[4*i+1]*kk4.y;
            s2 += qv[4*i+2]*kk4.z; s3 += qv[4*i+3]*kk4.w;
          }
          float s  = (s0+s1+s2+s3) * 0.125f;
          float mn = fmaxf(m, s);
          float corr = __expf(m - mn);
          float p    = __expf(s - mn);
          l = l*corr + p;
          const float4* vr4 = (const float4*)(s_v + k*HD);
          #pragma unroll
          for (int i = 0; i < 16; ++i) {
            float4 vv4 = vr4[i];
            ov[4*i  ] = ov[4*i  ]*corr + p*vv4.x;
            ov[4*i+1] = ov[4*i+1]*corr + p*vv4.y;
            ov[4*i+2] = ov[4*i+2]*corr + p*vv4.z;
            ov[4*i+3] = ov[4*i+3]*corr + p*vv4.w;
          }
          m = mn;
        }
        float rl = 1.f/l;
        #pragma unroll
        for (int d = 0; d < HD; ++d) ov[d] *= rl;
        for (int c = 0; c < CC; ++c) {
          const float* wr = st_wo + (long)base*CC + c;
          float a0=0.f,a1=0.f,a2=0.f,a3=0.f;
          #pragma unroll
          for (int d = 0; d < HD; d += 4) {
            a0 += ov[d  ]*wr[(long)(d  )*CC]; a1 += ov[d+1]*wr[(long)(d+1)*CC];
            a2 += ov[d+2]*wr[(long)(d+2)*CC]; a3 += ov[d+3]*wr[(long)(d+3)*CC];
          }
          s_comb[c*CPAD + q] += a0+a1+a2+a3;
        }
      }
    }
  }

  {
    float* s_k = s_kv;
    float* s_v = s_kv + TT*HD;
    for (int h = 0; h < HH; ++h) {
      const int base = h*HD;
      __syncthreads();
      {
        const int d = tid & 63, krow = tid >> 6;
        for (int kk = 0; kk < TT/2; ++kk) {
          int k = kk*2 + krow;
          float aK = ts_bk[base + d], aV = ts_bv[base + d];
          for (int c = 0; c < CC; ++c) {
            float a = s_sp[c*TT + k];
            aK += a * ts_wk[(long)c*EE + base + d];
            aV += a * ts_wv[(long)c*EE + base + d];
          }
          s_k[k*HD + d] = aK;
          s_v[k*HD + d] = aV;
        }
      }
      __syncthreads();
      if (tid < CC) {
        const int q = tid;
        float qv[HD];
        #pragma unroll
        for (int d = 0; d < HD; ++d) qv[d] = ts_bq[base + d];
        const float* tr = s_tp + q*TT;
        for (int t = 0; t < TT; ++t) {
          float a = tr[t];
          const float* wr = ts_wq + (long)t*EE + base;
          #pragma unroll
          for (int d = 0; d < HD; ++d) qv[d] += a * wr[d];
        }
        float m = -INFINITY, l = 0.f, ov[HD];
        #pragma unroll
        for (int d = 0; d < HD; ++d) ov[d] = 0.f;
        for (int k = 0; k < TT; ++k) {
          const float4* kr4 = (const float4*)(s_k + k*HD);
          float s0=0.f,s1=0.f,s2=0.f,s3=0.f;
          #pragma unroll
          for (int i = 0; i < 16; ++i) {
            float4 kk4 = kr4[i];
            s0 += qv[4*i  ]*kk4.x; s1 += qv[4*i+1]*kk4.y;
            s2 += qv[4*i+2]*kk4.z; s3 += qv[4*i+3]*kk4.w;
          }
          float s  = (s0+s1+s2+s3) * 0.125f;
          float mn = fmaxf(m, s);
          float corr = __expf(m - mn);
          float p    = __expf(s - mn);
          l = l*corr + p;
          const float4* vr4 = (const float4*)(s_v + k*HD);
          #pragma unroll
          for (int i = 0; i < 16; ++i) {
            float4 vv4 = vr4[i];
            ov[4*i  ] = ov[4*i  ]*corr + p*vv4.x;
            ov[4*i+1] = ov[4*i+1]*corr + p*vv4.y;
            ov[4*i+2] = ov[4*i+2]*corr + p*vv4.z;
            ov[4*i+3] = ov[4*i+3]*corr + p*vv4.w;
          }
          m = mn;
        }
        float rl = 1.f/l;
        #pragma unroll
        for (int d = 0; d < HD; ++d) ov[d] *= rl;
        for (int t = 0; t < TT; ++t) {
          const float* wr = ts_wo + (long)base*TT + t;
          float a0=0.f,a1=0.f,a2=0.f,a3=0.f;
          #pragma unroll
          for (int d = 0; d < HD; d += 4) {
            a0 += ov[d  ]*wr[(long)(d  )*TT]; a1 += ov[d+1]*wr[(long)(d+1)*TT];
            a2 += ov[d+2]*wr[(long)(d+2)*TT]; a3 += ov[d+3]*wr[(long)(d+3)*TT];
          }
          s_comb[q*CPAD + t] += a0+a1+a2+a3;
        }
      }
    }
  }
  __syncthreads();

  if (tid < TT) {
    const int t = tid;
    float mean = 0.f;
    for (int c = 0; c < CC; ++c) mean += s_comb[c*CPAD + t];
    mean *= (1.f/CC);
    float var = 0.f;
    for (int c = 0; c < CC; ++c) { float dv = s_comb[c*CPAD + t] - mean; var += dv*dv; }
    var *= (1.f/CC);
    float rstd = 1.f / sqrtf(var + 1e-5f);
    for (int c = 0; c < CC; ++c) {
      float y = (s_comb[c*CPAD + t] - mean) * rstd * alpha[c] + beta[c];
      s_comb[c*CPAD + t] = y + x[bb + c*TT + t];
    }
  }
  __syncthreads();

  float* s_w = s_kv;
  for (int o = tid; o < TT*TT; o += 128) {
    int f = o / TT, t = o - f*TT;
    s_w[t*TT + f] = fcw[o];
  }
  __syncthreads();

  for (int o = tid; o < CC*TT; o += 128) {
    int c = o / TT, f = o - c*TT;
    const float* cr = s_comb + c*CPAD;
    float a0 = 0.f, a1 = 0.f;
    for (int t = 0; t < TT; t += 2) {
      a0 += cr[t    ] * s_w[(t    )*TT + f];
      a1 += cr[t + 1] * s_w[(t + 1)*TT + f];
    }
    out[bb + o] = tanhf(a0 + a1 + fcb[f]);
  }
}

// ---------------------------------------------------------------- launch
extern "C" void kernel_launch(void* const* d_in, const int* in_sizes, int n_in,
                              void* d_out, int out_size, void* d_ws, size_t ws_size,
                              hipStream_t stream) {
  const float* x     = (const float*)d_in[0];
  const float* adj   = (const float*)d_in[1];
  const float* sadj  = (const float*)d_in[2];
  const float* tmask = (const float*)d_in[3];
  const float* tadj  = (const float*)d_in[4];
  const float* st_wq = (const float*)d_in[5];  const float* st_bq = (const float*)d_in[6];
  const float* st_wk = (const float*)d_in[7];  const float* st_bk = (const float*)d_in[8];
  const float* st_wv = (const float*)d_in[9];  const float* st_bv = (const float*)d_in[10];
  const float* st_wo = (const float*)d_in[11]; const float* st_bo = (const float*)d_in[12];
  const float* ts_wq = (const float*)d_in[13]; const float* ts_bq = (const float*)d_in[14];
  const float* ts_wk = (const float*)d_in[15]; const float* ts_bk = (const float*)d_in[16];
  const float* ts_wv = (const float*)d_in[17]; const float* ts_bv = (const float*)d_in[18];
  const float* ts_wo = (const float*)d_in[19]; const float* ts_bo = (const float*)d_in[20];
  const float* alpha = (const float*)d_in[21]; const float* beta  = (const float*)d_in[22];
  const float* fcw   = (const float*)d_in[23]; const float* fcb   = (const float*)d_in[24];
  float* out = (float*)d_out;

  const int B = in_sizes[0] / (CC*TT);
  const size_t comb_bytes = (size_t)B * CC * TT * 4;
  const size_t w_bytes    = (size_t)W_TOTAL * 2;
  const size_t spt_bytes  = (size_t)B * SPT_R * SPT_S * 2;
  const size_t tp_bytes   = (size_t)B * TP_R * TP_S * 2;
  const size_t need_plain  = 2*comb_bytes + w_bytes + spt_bytes + tp_bytes;
  const size_t need_atomic =   comb_bytes + w_bytes + spt_bytes + tp_bytes;

  if (ws_size >= need_atomic) {
    const int plain = (ws_size >= need_plain) ? 1 : 0;
    const size_t cbuf = plain ? 2*comb_bytes : comb_bytes;
    float* c1      = (float*)d_ws;                       // plain: [B][T][C]; atomic: comb
    float* c2      = plain ? (float*)((char*)d_ws + comb_bytes) : nullptr;  // [B][C][T]
    bf16*  wsec    = (bf16*)((char*)d_ws + cbuf);
    bf16*  spT_all = (bf16*)((char*)d_ws + cbuf + w_bytes);
    bf16*  tp_all  = spT_all + (size_t)B * SPT_R * SPT_S;

    if (!plain) hipMemsetAsync(c1, 0, comb_bytes, stream);
    // weight pre-transposes (one-off, tiny)
    k_tr<<<(512*128+255)/256, 256, 0, stream>>>(st_wk, wsec + W_STWK, TT, EE, EE, 128);
    k_tr<<<(512*128+255)/256, 256, 0, stream>>>(st_wv, wsec + W_STWV, TT, EE, EE, 128);
    k_tr<<<(512* 96+255)/256, 256, 0, stream>>>(st_wq, wsec + W_STWQ, CC, EE, EE,  96);
    k_tr<<<( 80*512+255)/256, 256, 0, stream>>>(st_wo, wsec + W_STWO, EE, CC,  80, 512);
    k_tr<<<(512* 96+255)/256, 256, 0, stream>>>(ts_wk, wsec + W_TSWK, CC, EE, EE,  96);
    k_tr<<<(512* 96+255)/256, 256, 0, stream>>>(ts_wv, wsec + W_TSWV, CC, EE, EE,  96);
    k_tr<<<(512*128+255)/256, 256, 0, stream>>>(ts_wq, wsec + W_TSWQ, TT, EE, EE, 128);
    k_tr<<<(112*512+255)/256, 256, 0, stream>>>(ts_wo, wsec + W_TSWO, EE, TT, 112, 512);

    k_prep<<<B, 256, 0, stream>>>(x, adj, sadj, tmask, tadj, spT_all, tp_all);
    k_attn<<<B*2, 512, 0, stream>>>(spT_all, tp_all, wsec,
                                    st_bq, st_bv, ts_bq, ts_bv,
                                    plain ? c1 : nullptr, c2,
                                    plain ? nullptr : c1, plain);
    k_epi<<<B, 256, 0, stream>>>(plain ? nullptr : c1, c1, c2, x,
                                 st_bo, ts_bo, alpha, beta, fcw, fcb, out, plain);
  } else {
    k_fused<<<B, 128, 0, stream>>>(x, adj, sadj, tmask, tadj,
                                   st_wq, st_bq, st_wk, st_bk, st_wv, st_bv, st_wo, st_bo,
                                   ts_wq, ts_bq, ts_wk, ts_bk, ts_wv, ts_bv, ts_wo, ts_bo,
                                   alpha, beta, fcw, fcb, out);
  }
}

// Round 4
// 1089.108 us; speedup vs baseline: 1.9644x; 1.0126x over previous
//
#include <hip/hip_runtime.h>
#include <hip/hip_bf16.h>
#include <math.h>
#include <stdint.h>

typedef __hip_bfloat16 bf16;
typedef __attribute__((ext_vector_type(8))) short short8;
typedef __attribute__((ext_vector_type(4))) short short4v;
typedef __attribute__((ext_vector_type(4))) float f32x4;
typedef __attribute__((ext_vector_type(4))) unsigned int uint4v;
union PF { uint4v u; short8 s; };

#define CC 66      // channels = J*DIMS
#define TT 100     // time steps
#define JJ 22      // joints
#define HH 8       // heads
#define HD 64      // head dim
#define EE 512     // embed
#define CPAD 101   // comb LDS stride in k_epi / k_fused

// padded token layouts in ws (zero-padded so MFMA K-chunks read clean zeros)
// enlarged vs r3: VtildeT-build B-operand needs token rows up to 128/96.
#define SPT_R 128  // spT rows (>=100)
#define SPT_S 96   // spT stride (>=66, mult of 32)
#define TP_R 96    // tp rows (>=66)
#define TP_S 128   // tp stride (>=100, mult of 32)

// weight section offsets (bf16 elements) inside ws
#define W_STWK 0                    // [512][128]
#define W_STWQ 65536                // [512][96]
#define W_TSWK 114688               // [512][96]
#define W_TSWQ 163840               // [512][128]
#define W_VST  229376               // WtildeT st: [8][80][128]
#define W_VTS  311296               // WtildeT ts: [8][112][96]
#define W_TOTAL 397312

__device__ __forceinline__ bf16 f2b(float v){ return __float2bfloat16(v); }
__device__ __forceinline__ short sb(float v){ __hip_bfloat16 h = __float2bfloat16(v); return *(short*)&h; }
__device__ __forceinline__ unsigned int pk2(float a, float b){
  unsigned short ua = (unsigned short)sb(a), ub = (unsigned short)sb(b);
  return (unsigned int)ua | ((unsigned int)ub << 16);
}

// ---------------------------------------------------------------- k_tr
__global__ void k_tr(const float* __restrict__ src, bf16* __restrict__ dst,
                     int Rsrc, int Csrc, int JP, int IP)
{
  int o = blockIdx.x*256 + threadIdx.x;
  if (o >= JP*IP) return;
  int j = o / IP, i = o - j*IP;
  float v = (j < Csrc && i < Rsrc) ? src[(long)i*Csrc + j] : 0.f;
  dst[o] = f2b(v);
}

// ---------------------------------------------------------------- k_wt
// WtildeT[h][o][k] = sum_d wv[k][h*64+d] * wo[h*64+d][o]   (zero-padded)
// thread map: o fastest -> wo reads coalesced, wv reads wave-uniform.
__global__ __launch_bounds__(256) void k_wt(
    const float* __restrict__ wv, const float* __restrict__ wo,
    bf16* __restrict__ dst, int OUT, int KDIM, int OP, int KP)
{
  int idx = blockIdx.x*256 + threadIdx.x;
  if (idx >= 8*OP*KP) return;
  int o = idx % OP;
  int hk = idx / OP;
  int k = hk % KP, h = hk / KP;
  float acc = 0.f;
  if (o < OUT && k < KDIM) {
    const float* wvp = wv + (long)k*EE + h*64;
    const float* wop = wo + (long)(h*64)*OUT + o;
    #pragma unroll 8
    for (int d = 0; d < 64; ++d) acc += wvp[d] * wop[(long)d*OUT];
  }
  dst[(long)h*OP*KP + (long)o*KP + k] = f2b(acc);
}

// ---------------------------------------------------------------- k_bias2
// bias2[0..127]  = st_bo[c] + sum_e st_bv[e]*st_wo[e][c]
// bias2[128..255]= ts_bo[t] + sum_e ts_bv[e]*ts_wo[e][t]
__global__ __launch_bounds__(256) void k_bias2(
    const float* __restrict__ st_bo, const float* __restrict__ st_bv,
    const float* __restrict__ st_wo,
    const float* __restrict__ ts_bo, const float* __restrict__ ts_bv,
    const float* __restrict__ ts_wo,
    float* __restrict__ bias2)
{
  int tid = threadIdx.x;
  if (tid < 128) {
    int c = tid; float a = 0.f;
    if (c < CC) {
      a = st_bo[c];
      for (int e = 0; e < EE; ++e) a += st_bv[e] * st_wo[(long)e*CC + c];
    }
    bias2[tid] = a;
  } else {
    int t = tid - 128; float a = 0.f;
    if (t < TT) {
      a = ts_bo[t];
      for (int e = 0; e < EE; ++e) a += ts_bv[e] * ts_wo[(long)e*TT + t];
    }
    bias2[tid] = a;
  }
}

// ---------------------------------------------------------------- k_prep
__global__ __launch_bounds__(256) void k_prep(
    const float* __restrict__ x, const float* __restrict__ adj,
    const float* __restrict__ sadj, const float* __restrict__ tmask,
    const float* __restrict__ tadj,
    bf16* __restrict__ spT_all, bf16* __restrict__ tp_all)
{
  __shared__ float s_x[CC*TT];
  __shared__ float s_Mt[TT*TT];
  __shared__ float s_A[JJ*JJ];
  __shared__ float s_dis[JJ];
  const int b = blockIdx.x, tid = threadIdx.x;
  const long bb = (long)b * (CC*TT);

  if (tid < JJ) {
    float dsum = 0.f;
    for (int i = 0; i < JJ; ++i) dsum += adj[tid*JJ + i];
    s_dis[tid] = dsum > 0.f ? rsqrtf(dsum) : 0.f;
  }
  for (int o = tid; o < CC*TT; o += 256) s_x[o] = x[bb + o];
  for (int o = tid; o < TT*TT; o += 256) {
    int f = o / TT, t = o - f*TT;
    s_Mt[t*TT + f] = tadj[o] * tmask[o];
  }
  __syncthreads();
  for (int o = tid; o < JJ*JJ; o += 256) {
    int v = o / JJ, j = o - v*JJ;
    s_A[o] = sadj[o] * adj[o] * s_dis[v] * s_dis[j];
  }
  __syncthreads();

  bf16* spT = spT_all + (long)b * (SPT_R*SPT_S);
  bf16* tp  = tp_all  + (long)b * (TP_R*TP_S);

  for (int o = tid; o < SPT_R*SPT_S; o += 256) {
    int t = o / SPT_S, c = o - t*SPT_S;
    float acc = 0.f;
    if (t < TT && c < CC) {
      int v = c / 3, dd = c - v*3;
      for (int j = 0; j < JJ; ++j) acc += s_A[v*JJ + j] * s_x[(j*3 + dd)*TT + t];
    }
    spT[o] = f2b(acc);
  }
  for (int o = tid; o < TP_R*TP_S; o += 256) {
    int n = o / TP_S, f = o - n*TP_S;
    float acc = 0.f;
    if (n < CC && f < TT) {
      float a0 = 0.f, a1 = 0.f;
      for (int t = 0; t < TT; t += 2) {
        a0 += s_x[n*TT + t    ] * s_Mt[(t    )*TT + f];
        a1 += s_x[n*TT + t + 1] * s_Mt[(t + 1)*TT + f];
      }
      acc = a0 + a1;
    }
    tp[o] = f2b(acc);
  }
}

// ---------------------------------------------------------------- MFMA helper
// A[m=lane&15][k=quad*8+j]; B[n=lane&15][k=quad*8+j]; D col=lane&15,row=quad*4+reg.
template<int Mt, int Nt, int KCH, int SA, int SB, int SD, bool SWA, bool SWB, bool SWD>
__device__ __forceinline__ void mm_tiles_t(
    const short* __restrict__ Am, const short* __restrict__ Bm,
    short* __restrict__ D, const float* __restrict__ bias, float scale,
    int wave, int ln, int qd)
{
  constexpr int NTILE = Mt*Nt;
  constexpr int NU = (NTILE + 7) / 8;
  #pragma unroll
  for (int u = 0; u < NU; ++u) {
    int ti = u*8 + wave;
    if (ti < NTILE) {
      int mi = ti / Nt, ni = ti - mi*Nt;
      f32x4 acc = {0.f, 0.f, 0.f, 0.f};
      const int ar = mi*16 + ln, br = ni*16 + ln;
      const int sza = SWA ? ((ar&7)<<3) : 0;
      const int szb = SWB ? ((br&7)<<3) : 0;
      const short* ap = Am + (long)ar*SA;
      const short* bp = Bm + (long)br*SB;
      #pragma unroll
      for (int kc = 0; kc < KCH; ++kc) {
        short8 af = *(const short8*)(ap + ((qd*8 + kc*32) ^ sza));
        short8 bf = *(const short8*)(bp + ((qd*8 + kc*32) ^ szb));
        acc = __builtin_amdgcn_mfma_f32_16x16x32_bf16(af, bf, acc, 0, 0, 0);
      }
      int col = ni*16 + ln;
      float bv_ = bias ? bias[col] : 0.f;
      #pragma unroll
      for (int r = 0; r < 4; ++r) {
        int row = mi*16 + qd*4 + r;
        int cs = SWD ? (col ^ ((row&7)<<3)) : col;
        D[row*SD + cs] = sb((acc[r] + bv_) * scale);
      }
    }
  }
}

// ---------------------------------------------------------------- attn body
// A=0: q = spatial tokens (100), kv = temporal (66), out cols = 66
// A=1: q = temporal tokens (66), kv = spatial (100), out cols = 100
// wo FUSED into V:  out_h = P_h @ (tok_kv @ Wtilde_h),  Wtilde = wv_h @ wo_h.
// Per head: 1 coop build phase (K, Q, VtildeT; 2 barriers), then each wave
// (wave<MQ) owns one 16-row q-tile: S^T -> in-register softmax (2 shfl_xor) ->
// in-register P fragments (shfl dance, no LDS) -> PVtilde accumulating
// directly into persistent accO. No Oproj step, no P/O LDS round-trips.
template<int A>
__device__ __forceinline__ void attn_body(
    short* __restrict__ SMEM,
    const bf16* __restrict__ spT_all, const bf16* __restrict__ tp_all,
    const bf16* __restrict__ wsec_,
    const float* __restrict__ st_bq, const float* __restrict__ ts_bq,
    float* __restrict__ o1, float* __restrict__ o2, float* __restrict__ comb_g,
    int plain)
{
  constexpr int QROWS = A ? 66 : 100;
  constexpr int KVR   = A ? 100 : 66;   // kv real rows
  constexpr int OUTD  = A ? 100 : 66;   // out cols
  constexpr int MQ  = A ? 5 : 7;        // q tiles
  constexpr int MKV = A ? 7 : 5;        // kv tiles (S^T m-dim)
  constexpr int MO  = A ? 7 : 5;        // out-col tiles
  constexpr int NVT = A ? 8 : 6;        // VtildeT build n-tiles (kv cols/16)
  constexpr int QCH = A ? 4 : 3;        // q-proj k-chunks (token feat dim)
  constexpr int KCH = A ? 3 : 4;        // k-proj / Vtilde k-chunks
  constexpr int PCH = A ? 4 : 3;        // PVtilde kv chunks
  constexpr int SAQ = A ? TP_S : SPT_S;
  constexpr int SAK = A ? SPT_S : TP_S;
  constexpr int VTS = A ? 128 : 104;    // Z3 stride (128 swizzled / 104 plain)
  constexpr bool VSW = A ? true : false;

  short* Z1 = SMEM;                  // K [MKV*16][64] swz
  short* Z2 = Z1 + MKV*16*64;        // Q [MQ*16][64] swz
  short* Z3 = Z2 + MQ*16*64;         // VtildeT [MO*16][VTS]

  const int b = blockIdx.x >> 1, tid = threadIdx.x;
  const long bb = (long)b * (CC*TT);
  const int wave = tid >> 6, lane = tid & 63, ln = lane & 15, qd = lane >> 4;

  const short* Aq = (const short*)(A ? (tp_all  + (long)b*TP_R*TP_S)
                                     : (spT_all + (long)b*SPT_R*SPT_S));
  const short* Ak = (const short*)(A ? (spT_all + (long)b*SPT_R*SPT_S)
                                     : (tp_all  + (long)b*TP_R*TP_S));
  const short* wsec = (const short*)wsec_;
  const short* wqT = wsec + (A ? W_TSWQ : W_STWQ);
  const short* wkT = wsec + (A ? W_TSWK : W_STWK);
  const short* wvt = wsec + (A ? W_VTS  : W_VST);   // per-head MO*16*SAK
  const float* bq = A ? ts_bq : st_bq;

  f32x4 accO[MO];
  { f32x4 z = {0.f,0.f,0.f,0.f};
    #pragma unroll
    for (int i = 0; i < MO; ++i) accO[i] = z; }

  for (int h = 0; h < HH; ++h) {
    const int base = h*HD;
    const short* wvh = wvt + (long)h*(MO*16*SAK);
    __syncthreads();   // Z zones free of prev head's readers
    // cooperative builds (disjoint LDS outputs, global operands)
    mm_tiles_t<MKV,4,KCH, SAK,SAK,64, false,false,true>(
        Ak, wkT + (long)base*SAK, Z1, nullptr, 1.f, wave, ln, qd);      // K
    mm_tiles_t<MQ,4,QCH, SAQ,SAQ,64, false,false,true>(
        Aq, wqT + (long)base*SAQ, Z2, bq + base, 1.f, wave, ln, qd);    // Q
    mm_tiles_t<MO,NVT,KCH, SAK,SAK,VTS, false,false,VSW>(
        wvh, Ak, Z3, nullptr, 1.f, wave, ln, qd);                       // VtildeT
    __syncthreads();

    if (wave < MQ) {
      // ---- S^T = K @ Q^T : lane holds q=ln (col), kv=ni*16+qd*4+r (rows)
      const int brQ = wave*16 + ln;
      const int szq = (brQ & 7) << 3;
      const short* bqp = Z2 + brQ*64;
      f32x4 s[MKV];
      #pragma unroll
      for (int ni = 0; ni < MKV; ++ni) {
        const int ar = ni*16 + ln;
        const int sza = (ar & 7) << 3;
        const short* ap = Z1 + ar*64;
        f32x4 acc = {0.f,0.f,0.f,0.f};
        acc = __builtin_amdgcn_mfma_f32_16x16x32_bf16(
            *(const short8*)(ap  + ((qd*8     ) ^ sza)),
            *(const short8*)(bqp + ((qd*8     ) ^ szq)), acc, 0,0,0);
        acc = __builtin_amdgcn_mfma_f32_16x16x32_bf16(
            *(const short8*)(ap  + ((qd*8 + 32) ^ sza)),
            *(const short8*)(bqp + ((qd*8 + 32) ^ szq)), acc, 0,0,0);
        s[ni] = acc;
      }
      // ---- mask pad kv + scale
      #pragma unroll
      for (int ni = 0; ni < MKV; ++ni) {
        #pragma unroll
        for (int r = 0; r < 4; ++r) {
          const int kv = ni*16 + qd*4 + r;
          s[ni][r] = (kv < KVR) ? s[ni][r]*0.125f : -1e30f;
        }
      }
      // ---- softmax over kv: own regs + quad groups (shfl_xor 16, 32)
      float mx = -1e30f;
      #pragma unroll
      for (int ni = 0; ni < MKV; ++ni)
        #pragma unroll
        for (int r = 0; r < 4; ++r) mx = fmaxf(mx, s[ni][r]);
      mx = fmaxf(mx, __shfl_xor(mx, 16));
      mx = fmaxf(mx, __shfl_xor(mx, 32));
      float l = 0.f;
      #pragma unroll
      for (int ni = 0; ni < MKV; ++ni)
        #pragma unroll
        for (int r = 0; r < 4; ++r) {
          float p = __expf(s[ni][r] - mx);   // masked: exp(-huge)=0
          s[ni][r] = p; l += p;
        }
      l += __shfl_xor(l, 16);
      l += __shfl_xor(l, 32);
      const float rs = 1.f / l;
      // ---- pack P rows (bf16 pairs); tiles beyond MKV are zero
      unsigned int plo[2*PCH], phi[2*PCH];
      #pragma unroll
      for (int ni = 0; ni < 2*PCH; ++ni) {
        if (ni < MKV) {
          plo[ni] = pk2(s[ni][0]*rs, s[ni][1]*rs);
          phi[ni] = pk2(s[ni][2]*rs, s[ni][3]*rs);
        } else { plo[ni] = 0u; phi[ni] = 0u; }
      }
      // ---- build B-fragments of P in-register (no LDS):
      // frag[kc] word w holds kv = kc*32 + qd*8 + {2w,2w+1} of row q=ln.
      // source lane = ln + 16*((qd&1)*2 + (w>>1)); tile = 2kc + (qd>>1).
      PF pf[PCH];
      #pragma unroll
      for (int kc = 0; kc < PCH; ++kc) {
        #pragma unroll
        for (int w = 0; w < 4; ++w) {
          const int srcLane = ln + 16*((qd & 1)*2 + (w >> 1));
          int va, vb;
          if (w & 1) {
            va = __shfl((int)phi[2*kc  ], srcLane, 64);
            vb = __shfl((int)phi[2*kc+1], srcLane, 64);
          } else {
            va = __shfl((int)plo[2*kc  ], srcLane, 64);
            vb = __shfl((int)plo[2*kc+1], srcLane, 64);
          }
          pf[kc].u[w] = (qd < 2) ? (unsigned int)va : (unsigned int)vb;
        }
      }
      // ---- out^T += Vtilde^T @ P^T : accumulate straight into accO
      #pragma unroll
      for (int oi = 0; oi < MO; ++oi) {
        const int ar = oi*16 + ln;
        const int sz = VSW ? ((ar & 7) << 3) : 0;
        const short* ap = Z3 + ar*VTS;
        f32x4 acc = accO[oi];
        #pragma unroll
        for (int kc = 0; kc < PCH; ++kc) {
          short8 af = *(const short8*)(ap + ((qd*8 + kc*32) ^ sz));
          acc = __builtin_amdgcn_mfma_f32_16x16x32_bf16(af, pf[kc].s, acc, 0,0,0);
        }
        accO[oi] = acc;
      }
    }
  }

  // out^T layout: lane q = wave*16+ln, col = oi*16+qd*4+r
  if (wave < MQ) {
    const int q = wave*16 + ln;
    #pragma unroll
    for (int oi = 0; oi < MO; ++oi) {
      #pragma unroll
      for (int r = 0; r < 4; ++r) {
        const int col = oi*16 + qd*4 + r;
        if (q < QROWS && col < OUTD) {
          float v = accO[oi][r];
          if (plain) {
            if (A) o2[bb + (long)q*TT + col] = v;   // [c][t]
            else   o1[bb + (long)q*CC + col] = v;   // [t][c]
          } else {
            long off = A ? ((long)q*TT + col) : ((long)col*TT + q);
            atomicAdd(&comb_g[bb + off], v);
          }
        }
      }
    }
  }
}

// ---------------------------------------------------------------- k_attn
// LDS = max(41216, 53248) = 53,248 B -> 3 blocks/CU by LDS; natural VGPR.
__global__ __launch_bounds__(512) void k_attn(
    const bf16* __restrict__ spT_all, const bf16* __restrict__ tp_all,
    const bf16* __restrict__ wsec,
    const float* __restrict__ st_bq, const float* __restrict__ ts_bq,
    float* __restrict__ o1, float* __restrict__ o2,
    float* __restrict__ comb_g, int plain)
{
  __shared__ __align__(16) short SMEM[26624];
  if (blockIdx.x & 1)
    attn_body<1>(SMEM,spT_all,tp_all,wsec,st_bq,ts_bq,o1,o2,comb_g,plain);
  else
    attn_body<0>(SMEM,spT_all,tp_all,wsec,st_bq,ts_bq,o1,o2,comb_g,plain);
}

// ---------------------------------------------------------------- k_epi
__global__ __launch_bounds__(256) void k_epi(
    const float* __restrict__ comb_g,
    const float* __restrict__ c1, const float* __restrict__ c2,
    const float* __restrict__ x,
    const float* __restrict__ bias2,
    const float* __restrict__ alpha, const float* __restrict__ beta,
    const float* __restrict__ fcw, const float* __restrict__ fcb,
    float* __restrict__ out, int plain)
{
  __shared__ float s_cb[CC*CPAD];
  __shared__ float s_w[TT*TT];
  const int b = blockIdx.x, tid = threadIdx.x;
  const long bb = (long)b * (CC*TT);

  for (int o = tid; o < CC*TT; o += 256) {
    int c = o / TT, t = o - c*TT;
    float v;
    if (plain) v = c1[bb + (long)t*CC + c] + c2[bb + o];
    else       v = comb_g[bb + o];
    s_cb[c*CPAD + t] = v + bias2[c] + bias2[128 + t];
  }
  for (int o = tid; o < TT*TT; o += 256) {
    int f = o / TT, t = o - f*TT;
    s_w[t*TT + f] = fcw[o];
  }
  __syncthreads();
  // LN over channels: 2 lanes per t-column (200 threads), shfl_xor combine
  if (tid < 2*TT) {
    const int t = tid >> 1, hf = tid & 1;
    float part = 0.f;
    for (int c = hf; c < CC; c += 2) part += s_cb[c*CPAD + t];
    float mean = (part + __shfl_xor(part, 1)) * (1.f/CC);
    float vp = 0.f;
    for (int c = hf; c < CC; c += 2) { float dv = s_cb[c*CPAD + t] - mean; vp += dv*dv; }
    float var = (vp + __shfl_xor(vp, 1)) * (1.f/CC);
    float rstd = 1.f / sqrtf(var + 1e-5f);
    for (int c = hf; c < CC; c += 2) {
      float y = (s_cb[c*CPAD + t] - mean) * rstd * alpha[c] + beta[c];
      s_cb[c*CPAD + t] = y + x[bb + c*TT + t];
    }
  }
  __syncthreads();
  for (int o = tid; o < CC*TT; o += 256) {
    int c = o / TT, f = o - c*TT;
    const float* cr = s_cb + c*CPAD;
    float a0 = 0.f, a1 = 0.f;
    for (int t = 0; t < TT; t += 2) {
      a0 += cr[t    ] * s_w[(t    )*TT + f];
      a1 += cr[t + 1] * s_w[(t + 1)*TT + f];
    }
    out[bb + o] = tanhf(a0 + a1 + fcb[f]);
  }
}

// ---------------------------------------------------------------- R4 fallback
__global__ __launch_bounds__(128) void k_fused(
    const float* __restrict__ x, const float* __restrict__ adj,
    const float* __restrict__ sadj, const float* __restrict__ tmask,
    const float* __restrict__ tadj,
    const float* __restrict__ st_wq, const float* __restrict__ st_bq,
    const float* __restrict__ st_wk, const float* __restrict__ st_bk,
    const float* __restrict__ st_wv, const float* __restrict__ st_bv,
    const float* __restrict__ st_wo, const float* __restrict__ st_bo,
    const float* __restrict__ ts_wq, const float* __restrict__ ts_bq,
    const float* __restrict__ ts_wk, const float* __restrict__ ts_bk,
    const float* __restrict__ ts_wv, const float* __restrict__ ts_bv,
    const float* __restrict__ ts_wo, const float* __restrict__ ts_bo,
    const float* __restrict__ alpha, const float* __restrict__ beta,
    const float* __restrict__ fcw, const float* __restrict__ fcb,
    float* __restrict__ out)
{
  __shared__ float s_sp[CC*TT];
  __shared__ float s_tp[CC*TT];
  __shared__ __align__(16) float s_kv[2*TT*HD];
  __shared__ float s_comb[CC*CPAD];
  __shared__ float s_A[JJ*JJ];
  __shared__ float s_dis[JJ];

  const int b = blockIdx.x, tid = threadIdx.x;
  const long bb = (long)b * (CC*TT);
  float* s_xs = s_comb;
  float* s_Mt = s_kv;

  if (tid < JJ) {
    float dsum = 0.f;
    for (int i = 0; i < JJ; ++i) dsum += adj[tid*JJ + i];
    s_dis[tid] = dsum > 0.f ? rsqrtf(dsum) : 0.f;
  }
  for (int o = tid; o < CC*TT; o += 128) s_xs[o] = x[bb + o];
  for (int o = tid; o < TT*TT; o += 128) {
    int f = o / TT, t = o - f*TT;
    s_Mt[t*TT + f] = tadj[o] * tmask[o];
  }
  __syncthreads();
  for (int o = tid; o < JJ*JJ; o += 128) {
    int v = o / JJ, j = o - v*JJ;
    s_A[o] = sadj[o] * adj[o] * s_dis[v] * s_dis[j];
  }
  __syncthreads();

  for (int o = tid; o < CC*TT; o += 128) {
    int c = o / TT, t = o - c*TT, v = c / 3, dd = c - v*3;
    float acc = 0.f;
    for (int j = 0; j < JJ; ++j) acc += s_A[v*JJ + j] * s_xs[(j*3 + dd)*TT + t];
    s_sp[o] = acc;
  }
  for (int o = tid; o < CC*TT; o += 128) {
    int n = o / TT, f = o - n*TT;
    float a0 = 0.f, a1 = 0.f;
    for (int t = 0; t < TT; t += 2) {
      a0 += s_xs[n*TT + t    ] * s_Mt[(t    )*TT + f];
      a1 += s_xs[n*TT + t + 1] * s_Mt[(t + 1)*TT + f];
    }
    s_tp[o] = a0 + a1;
  }
  __syncthreads();

  for (int o = tid; o < CC*TT; o += 128) {
    int c = o / TT, t = o - c*TT;
    s_comb[c*CPAD + t] = st_bo[c] + ts_bo[t];
  }

  {
    float* s_k = s_kv;
    float* s_v = s_kv + TT*HD;
    for (int h = 0; h < HH; ++h) {
      const int base = h*HD;
      __syncthreads();
      {
        const int d = tid & 63, krow = tid >> 6;
        for (int kk = 0; kk < CC/2; ++kk) {
          int k = kk*2 + krow;
          float aK = st_bk[base + d], aV = st_bv[base + d];
          const float* tr = s_tp + k*TT;
          for (int t = 0; t < TT; ++t) {
            float a = tr[t];
            aK += a * st_wk[(long)t*EE + base + d];
            aV += a * st_wv[(long)t*EE + base + d];
          }
          s_k[k*HD + d] = aK;
          s_v[k*HD + d] = aV;
        }
      }
      __syncthreads();
      if (tid < TT) {
        const int q = tid;
        float qv[HD];
        #pragma unroll
        for (int d = 0; d < HD; ++d) qv[d] = st_bq[base + d];
        for (int c = 0; c < CC; ++c) {
          float a = s_sp[c*TT + q];
          const float* wr = st_wq + (long)c*EE + base;
          #pragma unroll
          for (int d = 0; d < HD; ++d) qv[d] += a * wr[d];
        }
        float m = -INFINITY, l = 0.f, ov[HD];
        #pragma unroll
        for (int d = 0; d < HD; ++d) ov[d] = 0.f;
        for (int k = 0; k < CC; ++k) {
          const float4* kr4 = (const float4*)(s_k + k*HD);
          float s0=0.f,s1=0.f,s2=0.f,s3=0.f;
          #pragma unroll
          for (int i = 0; i < 16; ++i) {
            float4 kk4 = kr4[i];
            s0 += qv[4*i  ]*kk4.x; s1 += qv[4*i+1]*kk4.y;
            s2 += qv[4*i+2]*kk4.z; s3 += qv[4*i+3]*kk4.w;
          }
          float s  = (s0+s1+s2+s3) * 0.125f;
          float mn = fmaxf(m, s);
          float corr = __expf(m - mn);
          float p    = __expf(s - mn);
          l = l*corr + p;
          const float4* vr4 = (const float4*)(s_v + k*HD);
          #pragma unroll
          for (int i = 0; i < 16; ++i) {
            float4 vv4 = vr4[i];
            ov[4*i  ] = ov[4*i  ]*corr + p*vv4.x;
            ov[4*i+1] = ov[4*i+1]*corr + p*vv4.y;
            ov[4*i+2] = ov[4*i+2]*corr + p*vv4.z;
            ov[4*i+3] = ov[4*i+3]*corr + p*vv4.w;
          }
          m = mn;
        }
        float rl = 1.f/l;
        #pragma unroll
        for (int d = 0; d < HD; ++d) ov[d] *= rl;
        for (int c = 0; c < CC; ++c) {
          const float* wr = st_wo + (long)base*CC + c;
          float a0=0.f,a1=0.f,a2=0.f,a3=0.f;
          #pragma unroll
          for (int d = 0; d < HD; d += 4) {
            a0 += ov[d  ]*wr[(long)(d  )*CC]; a1 += ov[d+1]*wr[(long)(d+1)*CC];
            a2 += ov[d+2]*wr[(long)(d+2)*CC]; a3 += ov[d+3]*wr[(long)(d+3)*CC];
          }
          s_comb[c*CPAD + q] += a0+a1+a2+a3;
        }
      }
    }
  }

  {
    float* s_k = s_kv;
    float* s_v = s_kv + TT*HD;
    for (int h = 0; h < HH; ++h) {
      const int base = h*HD;
      __syncthreads();
      {
        const int d = tid & 63, krow = tid >> 6;
        for (int kk = 0; kk < TT/2; ++kk) {
          int k = kk*2 + krow;
          float aK = ts_bk[base + d], aV = ts_bv[base + d];
          for (int c = 0; c < CC; ++c) {
            float a = s_sp[c*TT + k];
            aK += a * ts_wk[(long)c*EE + base + d];
            aV += a * ts_wv[(long)c*EE + base + d];
          }
          s_k[k*HD + d] = aK;
          s_v[k*HD + d] = aV;
        }
      }
      __syncthreads();
      if (tid < CC) {
        const int q = tid;
        float qv[HD];
        #pragma unroll
        for (int d = 0; d < HD; ++d) qv[d] = ts_bq[base + d];
        const float* tr = s_tp + q*TT;
        for (int t = 0; t < TT; ++t) {
          float a = tr[t];
          const float* wr = ts_wq + (long)t*EE + base;
          #pragma unroll
          for (int d = 0; d < HD; ++d) qv[d] += a * wr[d];
        }
        float m = -INFINITY, l = 0.f, ov[HD];
        #pragma unroll
        for (int d = 0; d < HD; ++d) ov[d] = 0.f;
        for (int k = 0; k < TT; ++k) {
          const float4* kr4 = (const float4*)(s_k + k*HD);
          float s0=0.f,s1=0.f,s2=0.f,s3=0.f;
          #pragma unroll
          for (int i = 0; i < 16; ++i) {
            float4 kk4 = kr4[i];
            s0 += qv[4*i  ]*kk4.x; s1 += qv[4*i+1]*kk4.y;
            s2 += qv[4*i+2]*kk4.z; s3 += qv[4*i+3]*kk4.w;
          }
          float s  = (s0+s1+s2+s3) * 0.125f;
          float mn = fmaxf(m, s);
          float corr = __expf(m - mn);
          float p    = __expf(s - mn);
          l = l*corr + p;
          const float4* vr4 = (const float4*)(s_v + k*HD);
          #pragma unroll
          for (int i = 0; i < 16; ++i) {
            float4 vv4 = vr4[i];
            ov[4*i  ] = ov[4*i  ]*corr + p*vv4.x;
            ov[4*i+1] = ov[4*i+1]*corr + p*vv4.y;
            ov[4*i+2] = ov[4*i+2]*corr + p*vv4.z;
            ov[4*i+3] = ov[4*i+3]*corr + p*vv4.w;
          }
          m = mn;
        }
        float rl = 1.f/l;
        #pragma unroll
        for (int d = 0; d < HD; ++d) ov[d] *= rl;
        for (int t = 0; t < TT; ++t) {
          const float* wr = ts_wo + (long)base*TT + t;
          float a0=0.f,a1=0.f,a2=0.f,a3=0.f;
          #pragma unroll
          for (int d = 0; d < HD; d += 4) {
            a0 += ov[d  ]*wr[(long)(d  )*TT]; a1 += ov[d+1]*wr[(long)(d+1)*TT];
            a2 += ov[d+2]*wr[(long)(d+2)*TT]; a3 += ov[d+3]*wr[(long)(d+3)*TT];
          }
          s_comb[q*CPAD + t] += a0+a1+a2+a3;
        }
      }
    }
  }
  __syncthreads();

  if (tid < TT) {
    const int t = tid;
    float mean = 0.f;
    for (int c = 0; c < CC; ++c) mean += s_comb[c*CPAD + t];
    mean *= (1.f/CC);
    float var = 0.f;
    for (int c = 0; c < CC; ++c) { float dv = s_comb[c*CPAD + t] - mean; var += dv*dv; }
    var *= (1.f/CC);
    float rstd = 1.f / sqrtf(var + 1e-5f);
    for (int c = 0; c < CC; ++c) {
      float y = (s_comb[c*CPAD + t] - mean) * rstd * alpha[c] + beta[c];
      s_comb[c*CPAD + t] = y + x[bb + c*TT + t];
    }
  }
  __syncthreads();

  float* s_w = s_kv;
  for (int o = tid; o < TT*TT; o += 128) {
    int f = o / TT, t = o - f*TT;
    s_w[t*TT + f] = fcw[o];
  }
  __syncthreads();

  for (int o = tid; o < CC*TT; o += 128) {
    int c = o / TT, f = o - c*TT;
    const float* cr = s_comb + c*CPAD;
    float a0 = 0.f, a1 = 0.f;
    for (int t = 0; t < TT; t += 2) {
      a0 += cr[t    ] * s_w[(t    )*TT + f];
      a1 += cr[t + 1] * s_w[(t + 1)*TT + f];
    }
    out[bb + o] = tanhf(a0 + a1 + fcb[f]);
  }
}

// ---------------------------------------------------------------- launch
extern "C" void kernel_launch(void* const* d_in, const int* in_sizes, int n_in,
                              void* d_out, int out_size, void* d_ws, size_t ws_size,
                              hipStream_t stream) {
  const float* x     = (const float*)d_in[0];
  const float* adj   = (const float*)d_in[1];
  const float* sadj  = (const float*)d_in[2];
  const float* tmask = (const float*)d_in[3];
  const float* tadj  = (const float*)d_in[4];
  const float* st_wq = (const float*)d_in[5];  const float* st_bq = (const float*)d_in[6];
  const float* st_wk = (const float*)d_in[7];  const float* st_bk = (const float*)d_in[8];
  const float* st_wv = (const float*)d_in[9];  const float* st_bv = (const float*)d_in[10];
  const float* st_wo = (const float*)d_in[11]; const float* st_bo = (const float*)d_in[12];
  const float* ts_wq = (const float*)d_in[13]; const float* ts_bq = (const float*)d_in[14];
  const float* ts_wk = (const float*)d_in[15]; const float* ts_bk = (const float*)d_in[16];
  const float* ts_wv = (const float*)d_in[17]; const float* ts_bv = (const float*)d_in[18];
  const float* ts_wo = (const float*)d_in[19]; const float* ts_bo = (const float*)d_in[20];
  const float* alpha = (const float*)d_in[21]; const float* beta  = (const float*)d_in[22];
  const float* fcw   = (const float*)d_in[23]; const float* fcb   = (const float*)d_in[24];
  float* out = (float*)d_out;

  const int B = in_sizes[0] / (CC*TT);
  const size_t comb_bytes = (size_t)B * CC * TT * 4;
  const size_t w_bytes    = (size_t)W_TOTAL * 2 + 1024;   // + bias2 floats
  const size_t spt_bytes  = (size_t)B * SPT_R * SPT_S * 2;
  const size_t tp_bytes   = (size_t)B * TP_R * TP_S * 2;
  const size_t need_plain  = 2*comb_bytes + w_bytes + spt_bytes + tp_bytes;
  const size_t need_atomic =   comb_bytes + w_bytes + spt_bytes + tp_bytes;

  if (ws_size >= need_atomic) {
    const int plain = (ws_size >= need_plain) ? 1 : 0;
    const size_t cbuf = plain ? 2*comb_bytes : comb_bytes;
    float* c1      = (float*)d_ws;                       // plain: [B][T][C]; atomic: comb
    float* c2      = plain ? (float*)((char*)d_ws + comb_bytes) : nullptr;  // [B][C][T]
    bf16*  wsec    = (bf16*)((char*)d_ws + cbuf);
    float* bias2   = (float*)((char*)d_ws + cbuf + (size_t)W_TOTAL*2);
    bf16*  spT_all = (bf16*)((char*)d_ws + cbuf + w_bytes);
    bf16*  tp_all  = spT_all + (size_t)B * SPT_R * SPT_S;

    if (!plain) hipMemsetAsync(c1, 0, comb_bytes, stream);
    // weight pre-transposes + Wtilde + folded bias (one-off, tiny)
    k_tr<<<(512*128+255)/256, 256, 0, stream>>>(st_wk, wsec + W_STWK, TT, EE, EE, 128);
    k_tr<<<(512* 96+255)/256, 256, 0, stream>>>(st_wq, wsec + W_STWQ, CC, EE, EE,  96);
    k_tr<<<(512* 96+255)/256, 256, 0, stream>>>(ts_wk, wsec + W_TSWK, CC, EE, EE,  96);
    k_tr<<<(512*128+255)/256, 256, 0, stream>>>(ts_wq, wsec + W_TSWQ, TT, EE, EE, 128);
    k_wt<<<(8*80*128+255)/256, 256, 0, stream>>>(st_wv, st_wo, wsec + W_VST, CC, TT,  80, 128);
    k_wt<<<(8*112*96+255)/256, 256, 0, stream>>>(ts_wv, ts_wo, wsec + W_VTS, TT, CC, 112,  96);
    k_bias2<<<1, 256, 0, stream>>>(st_bo, st_bv, st_wo, ts_bo, ts_bv, ts_wo, bias2);

    k_prep<<<B, 256, 0, stream>>>(x, adj, sadj, tmask, tadj, spT_all, tp_all);
    k_attn<<<B*2, 512, 0, stream>>>(spT_all, tp_all, wsec, st_bq, ts_bq,
                                    plain ? c1 : nullptr, c2,
                                    plain ? nullptr : c1, plain);
    k_epi<<<B, 256, 0, stream>>>(plain ? nullptr : c1, c1, c2, x, bias2,
                                 alpha, beta, fcw, fcb, out, plain);
  } else {
    k_fused<<<B, 128, 0, stream>>>(x, adj, sadj, tmask, tadj,
                                   st_wq, st_bq, st_wk, st_bk, st_wv, st_bv, st_wo, st_bo,
                                   ts_wq, ts_bq, ts_wk, ts_bk, ts_wv, ts_bv, ts_wo, ts_bo,
                                   alpha, beta, fcw, fcb, out);
  }
}

// Round 5
// 969.724 us; speedup vs baseline: 2.2062x; 1.1231x over previous
//
#include <hip/hip_runtime.h>
#include <hip/hip_bf16.h>
#include <math.h>
#include <stdint.h>

typedef __hip_bfloat16 bf16;
typedef __attribute__((ext_vector_type(8))) short short8;
typedef __attribute__((ext_vector_type(4))) short short4v;
typedef __attribute__((ext_vector_type(4))) float f32x4;
typedef __attribute__((ext_vector_type(4))) unsigned int uint4v;
union PF { uint4v u; short8 s; };

#define CC 66      // channels = J*DIMS
#define TT 100     // time steps
#define JJ 22      // joints
#define HH 8       // heads
#define HD 64      // head dim
#define EE 512     // embed
#define CPAD 101   // comb LDS stride in k_epi / k_fused

// padded token layouts in ws (zero-padded so MFMA K-chunks read clean zeros)
#define SPT_R 128  // spT rows (>=100)
#define SPT_S 96   // spT stride (>=66, mult of 32)
#define TP_R 96    // tp rows (>=66)
#define TP_S 128   // tp stride (>=100, mult of 32)

// weight section offsets (bf16 elements) inside ws
#define W_STWK 0                    // [512][128]
#define W_STWQ 65536                // [512][96]
#define W_TSWK 114688               // [512][96]
#define W_TSWQ 163840               // [512][128]
#define W_VST  229376               // WtildeT st: [8][80][128]
#define W_VTS  311296               // WtildeT ts: [8][112][96]
#define W_TOTAL 397312

__device__ __forceinline__ bf16 f2b(float v){ return __float2bfloat16(v); }
__device__ __forceinline__ short sb(float v){ __hip_bfloat16 h = __float2bfloat16(v); return *(short*)&h; }
__device__ __forceinline__ unsigned int pk2(float a, float b){
  unsigned short ua = (unsigned short)sb(a), ub = (unsigned short)sb(b);
  return (unsigned int)ua | ((unsigned int)ub << 16);
}

// ---------------------------------------------------------------- k_wprep
// One launch doing all weight preprocessing: 4 transposes, 2 Wtilde GEMMs,
// folded bias. Section offsets in 256-thread blocks.
__device__ __forceinline__ void tr_body(
    const float* __restrict__ src, bf16* __restrict__ dst,
    int Rsrc, int Csrc, int JP, int IP, int blk, int tid)
{
  int o = blk*256 + tid;
  if (o >= JP*IP) return;
  int j = o / IP, i = o - j*IP;
  float v = (j < Csrc && i < Rsrc) ? src[(long)i*Csrc + j] : 0.f;
  dst[o] = f2b(v);
}

__device__ __forceinline__ void wt_body(
    const float* __restrict__ wv, const float* __restrict__ wo,
    bf16* __restrict__ dst, int OUT, int KDIM, int OP, int KP, int blk, int tid)
{
  int idx = blk*256 + tid;
  if (idx >= 8*OP*KP) return;
  int o = idx % OP;
  int hk = idx / OP;
  int k = hk % KP, h = hk / KP;
  float acc = 0.f;
  if (o < OUT && k < KDIM) {
    const float* wvp = wv + (long)k*EE + h*64;
    const float* wop = wo + (long)(h*64)*OUT + o;
    #pragma unroll 8
    for (int d = 0; d < 64; ++d) acc += wvp[d] * wop[(long)d*OUT];
  }
  dst[(long)h*OP*KP + (long)o*KP + k] = f2b(acc);
}

__global__ __launch_bounds__(256) void k_wprep(
    const float* __restrict__ st_wk, const float* __restrict__ st_wq,
    const float* __restrict__ ts_wk, const float* __restrict__ ts_wq,
    const float* __restrict__ st_wv, const float* __restrict__ st_wo,
    const float* __restrict__ ts_wv, const float* __restrict__ ts_wo,
    const float* __restrict__ st_bo, const float* __restrict__ st_bv,
    const float* __restrict__ ts_bo, const float* __restrict__ ts_bv,
    bf16* __restrict__ wsec, float* __restrict__ bias2)
{
  const int blk = blockIdx.x, tid = threadIdx.x;
  if      (blk <  256) tr_body(st_wk, wsec + W_STWK, TT, EE, EE, 128, blk,      tid);
  else if (blk <  448) tr_body(st_wq, wsec + W_STWQ, CC, EE, EE,  96, blk-256,  tid);
  else if (blk <  640) tr_body(ts_wk, wsec + W_TSWK, CC, EE, EE,  96, blk-448,  tid);
  else if (blk <  896) tr_body(ts_wq, wsec + W_TSWQ, TT, EE, EE, 128, blk-640,  tid);
  else if (blk < 1216) wt_body(st_wv, st_wo, wsec + W_VST, CC, TT,  80, 128, blk-896,  tid);
  else if (blk < 1552) wt_body(ts_wv, ts_wo, wsec + W_VTS, TT, CC, 112,  96, blk-1216, tid);
  else {
    if (tid < 128) {
      int c = tid; float a = 0.f;
      if (c < CC) {
        a = st_bo[c];
        for (int e = 0; e < EE; ++e) a += st_bv[e] * st_wo[(long)e*CC + c];
      }
      bias2[tid] = a;
    } else {
      int t = tid - 128; float a = 0.f;
      if (t < TT) {
        a = ts_bo[t];
        for (int e = 0; e < EE; ++e) a += ts_bv[e] * ts_wo[(long)e*TT + t];
      }
      bias2[tid] = a;
    }
  }
}

// ---------------------------------------------------------------- k_prep
__global__ __launch_bounds__(256) void k_prep(
    const float* __restrict__ x, const float* __restrict__ adj,
    const float* __restrict__ sadj, const float* __restrict__ tmask,
    const float* __restrict__ tadj,
    bf16* __restrict__ spT_all, bf16* __restrict__ tp_all)
{
  __shared__ float s_x[CC*TT];
  __shared__ float s_Mt[TT*TT];
  __shared__ float s_A[JJ*JJ];
  __shared__ float s_dis[JJ];
  const int b = blockIdx.x, tid = threadIdx.x;
  const long bb = (long)b * (CC*TT);

  if (tid < JJ) {
    float dsum = 0.f;
    for (int i = 0; i < JJ; ++i) dsum += adj[tid*JJ + i];
    s_dis[tid] = dsum > 0.f ? rsqrtf(dsum) : 0.f;
  }
  for (int o = tid; o < CC*TT; o += 256) s_x[o] = x[bb + o];
  for (int o = tid; o < TT*TT; o += 256) {
    int f = o / TT, t = o - f*TT;
    s_Mt[t*TT + f] = tadj[o] * tmask[o];
  }
  __syncthreads();
  for (int o = tid; o < JJ*JJ; o += 256) {
    int v = o / JJ, j = o - v*JJ;
    s_A[o] = sadj[o] * adj[o] * s_dis[v] * s_dis[j];
  }
  __syncthreads();

  bf16* spT = spT_all + (long)b * (SPT_R*SPT_S);
  bf16* tp  = tp_all  + (long)b * (TP_R*TP_S);

  for (int o = tid; o < SPT_R*SPT_S; o += 256) {
    int t = o / SPT_S, c = o - t*SPT_S;
    float acc = 0.f;
    if (t < TT && c < CC) {
      int v = c / 3, dd = c - v*3;
      for (int j = 0; j < JJ; ++j) acc += s_A[v*JJ + j] * s_x[(j*3 + dd)*TT + t];
    }
    spT[o] = f2b(acc);
  }
  for (int o = tid; o < TP_R*TP_S; o += 256) {
    int n = o / TP_S, f = o - n*TP_S;
    float acc = 0.f;
    if (n < CC && f < TT) {
      float a0 = 0.f, a1 = 0.f;
      for (int t = 0; t < TT; t += 2) {
        a0 += s_x[n*TT + t    ] * s_Mt[(t    )*TT + f];
        a1 += s_x[n*TT + t + 1] * s_Mt[(t + 1)*TT + f];
      }
      acc = a0 + a1;
    }
    tp[o] = f2b(acc);
  }
}

// ---------------------------------------------------------------- build helpers
// Swapped-operand builds: m-dim = consumer's k-dim, so the C-strip (4 rows,
// 1 col per lane) lands CONTIGUOUS in the zone row -> ONE ds_write_b64
// per tile (was 4x ds_write_b16). A-fragments register-cached per wave.
// Zone layout: Z[row][kdim], kdim stride SZ, XOR-swizzle ((row&7)<<3).

// K/Q builds: m = d (4 tiles of 16), n = token rows. 2 waves per m-tile.
template<int Nt, int KCH, int SA, int SB>
__device__ __forceinline__ void build_kq(
    const short* __restrict__ W, const short* __restrict__ Tok,
    short* __restrict__ Z, const float* __restrict__ rowbias,
    int wave, int ln, int qd)
{
  const int mi = wave & 3;
  const int d0 = mi*16 + qd*4;
  const short* ap = W + (long)(mi*16 + ln)*SA;
  short8 af[KCH];
  #pragma unroll
  for (int kc = 0; kc < KCH; ++kc) af[kc] = *(const short8*)(ap + qd*8 + kc*32);
  float rb0=0.f, rb1=0.f, rb2=0.f, rb3=0.f;
  if (rowbias) { rb0=rowbias[d0]; rb1=rowbias[d0+1]; rb2=rowbias[d0+2]; rb3=rowbias[d0+3]; }
  constexpr int NU = (Nt + 1) / 2;
  #pragma unroll
  for (int u = 0; u < NU; ++u) {
    const int ni = (wave >> 2) + 2*u;
    if (ni < Nt) {
      const int row = ni*16 + ln;
      const short* bp = Tok + (long)row*SB;
      f32x4 acc = {0.f,0.f,0.f,0.f};
      #pragma unroll
      for (int kc = 0; kc < KCH; ++kc)
        acc = __builtin_amdgcn_mfma_f32_16x16x32_bf16(
            af[kc], *(const short8*)(bp + qd*8 + kc*32), acc, 0,0,0);
      short4v pk;
      pk.x = sb(acc[0]+rb0); pk.y = sb(acc[1]+rb1);
      pk.z = sb(acc[2]+rb2); pk.w = sb(acc[3]+rb3);
      *(short4v*)(Z + row*64 + (d0 ^ ((ln & 7) << 3))) = pk;
    }
  }
}

// VtildeT build: m = kv (Mt tiles), n = out rows. Wave w<Mt owns m-tile w.
template<int Mt, int Nt, int KCH, int SA, int SB, int SZ>
__device__ __forceinline__ void build_vt(
    const short* __restrict__ Tok, const short* __restrict__ Wv,
    short* __restrict__ Z, int wave, int ln, int qd)
{
  if (wave >= Mt) return;
  const int mi = wave;
  const int k0 = mi*16 + qd*4;
  const short* ap = Tok + (long)(mi*16 + ln)*SA;
  short8 af[KCH];
  #pragma unroll
  for (int kc = 0; kc < KCH; ++kc) af[kc] = *(const short8*)(ap + qd*8 + kc*32);
  #pragma unroll
  for (int ni = 0; ni < Nt; ++ni) {
    const int row = ni*16 + ln;
    const short* bp = Wv + (long)row*SB;
    f32x4 acc = {0.f,0.f,0.f,0.f};
    #pragma unroll
    for (int kc = 0; kc < KCH; ++kc)
      acc = __builtin_amdgcn_mfma_f32_16x16x32_bf16(
          af[kc], *(const short8*)(bp + qd*8 + kc*32), acc, 0,0,0);
    short4v pk;
    pk.x = sb(acc[0]); pk.y = sb(acc[1]); pk.z = sb(acc[2]); pk.w = sb(acc[3]);
    *(short4v*)(Z + row*SZ + (k0 ^ ((ln & 7) << 3))) = pk;
  }
}

// ---------------------------------------------------------------- attn body
// A=0: q = spatial (100), kv = temporal (66), out = 66
// A=1: q = temporal (66), kv = spatial (100), out = 100
// wo fused into V (Wtilde = wv_h @ wo_h); bv@wo folded into epilogue bias.
template<int A>
__device__ __forceinline__ void attn_body(
    short* __restrict__ SMEM,
    const bf16* __restrict__ spT_all, const bf16* __restrict__ tp_all,
    const bf16* __restrict__ wsec_,
    const float* __restrict__ st_bq, const float* __restrict__ ts_bq,
    float* __restrict__ o1, float* __restrict__ o2, float* __restrict__ comb_g,
    int plain)
{
  constexpr int QROWS = A ? 66 : 100;
  constexpr int KVR   = A ? 100 : 66;
  constexpr int OUTD  = A ? 100 : 66;
  constexpr int MQ  = A ? 5 : 7;        // q tiles
  constexpr int MKV = A ? 7 : 5;        // kv tiles
  constexpr int MO  = A ? 7 : 5;        // out tiles
  constexpr int QCH = A ? 4 : 3;        // q/k-proj feat chunks (q side)
  constexpr int KCH = A ? 3 : 4;        // k-proj/Vtilde feat chunks (kv side)
  constexpr int PCH = A ? 4 : 3;        // PV kv chunks
  constexpr int SAQ = A ? TP_S : SPT_S;
  constexpr int SAK = A ? SPT_S : TP_S;
  constexpr int VTS = 128;              // Z3 kv stride (both flavors)

  short* Z1 = SMEM;                  // K  [MKV*16][64] swz
  short* Z2 = Z1 + MKV*16*64;        // Q  [MQ*16][64] swz
  short* Z3 = Z2 + MQ*16*64;         // VT [MO*16][128] swz

  const int b = blockIdx.x >> 1, tid = threadIdx.x;
  const long bb = (long)b * (CC*TT);
  const int wave = tid >> 6, lane = tid & 63, ln = lane & 15, qd = lane >> 4;
  const int msk = (ln & 7) << 3;

  const short* Aq = (const short*)(A ? (tp_all  + (long)b*TP_R*TP_S)
                                     : (spT_all + (long)b*SPT_R*SPT_S));
  const short* Ak = (const short*)(A ? (spT_all + (long)b*SPT_R*SPT_S)
                                     : (tp_all  + (long)b*TP_R*TP_S));
  const short* wsec = (const short*)wsec_;
  const short* wqT = wsec + (A ? W_TSWQ : W_STWQ);
  const short* wkT = wsec + (A ? W_TSWK : W_STWK);
  const short* wvt = wsec + (A ? W_VTS  : W_VST);
  const float* bq = A ? ts_bq : st_bq;

  // one-time zero of Z3 pad kv-cols [MKV*16, PCH*32) (swizzled positions);
  // builds rewrite only kv < MKV*16 each head, so these stay zero.
  for (int o = tid; o < MO*16*16; o += 512) {
    const int out = o >> 4, kv = MKV*16 + (o & 15);
    Z3[out*VTS + (kv ^ ((out & 7) << 3))] = 0;
  }

  f32x4 accO[MO];
  { f32x4 z = {0.f,0.f,0.f,0.f};
    #pragma unroll
    for (int i = 0; i < MO; ++i) accO[i] = z; }

  for (int h = 0; h < HH; ++h) {
    const int base = h*HD;
    __syncthreads();   // Z zones free of prev head's readers (h=0: init done)
    build_kq<MKV,KCH,SAK,SAK>(wkT + (long)base*SAK, Ak, Z1, nullptr, wave, ln, qd);
    build_kq<MQ, QCH,SAQ,SAQ>(wqT + (long)base*SAQ, Aq, Z2, bq + base, wave, ln, qd);
    build_vt<MKV,MO,KCH,SAK,SAK,VTS>(Ak, wvt + (long)h*(MO*16*SAK), Z3, wave, ln, qd);
    __syncthreads();

    if (wave < MQ) {
      // ---- S^T = K @ Q^T : lane holds q=ln, kv = ni*16+qd*4+r
      const short* bqp = Z2 + (wave*16 + ln)*64;
      const short8 qf0 = *(const short8*)(bqp + ((qd*8     ) ^ msk));
      const short8 qf1 = *(const short8*)(bqp + ((qd*8 + 32) ^ msk));
      f32x4 s[MKV];
      #pragma unroll
      for (int ni = 0; ni < MKV; ++ni) {
        const short* ap = Z1 + (ni*16 + ln)*64;
        f32x4 acc = {0.f,0.f,0.f,0.f};
        acc = __builtin_amdgcn_mfma_f32_16x16x32_bf16(
            *(const short8*)(ap + ((qd*8     ) ^ msk)), qf0, acc, 0,0,0);
        acc = __builtin_amdgcn_mfma_f32_16x16x32_bf16(
            *(const short8*)(ap + ((qd*8 + 32) ^ msk)), qf1, acc, 0,0,0);
        s[ni] = acc;
      }
      // ---- mask pad kv + scale
      #pragma unroll
      for (int ni = 0; ni < MKV; ++ni) {
        #pragma unroll
        for (int r = 0; r < 4; ++r) {
          const int kv = ni*16 + qd*4 + r;
          s[ni][r] = (kv < KVR) ? s[ni][r]*0.125f : -1e30f;
        }
      }
      // ---- softmax over kv (own regs + shfl_xor 16, 32)
      float mx = -1e30f;
      #pragma unroll
      for (int ni = 0; ni < MKV; ++ni)
        #pragma unroll
        for (int r = 0; r < 4; ++r) mx = fmaxf(mx, s[ni][r]);
      mx = fmaxf(mx, __shfl_xor(mx, 16));
      mx = fmaxf(mx, __shfl_xor(mx, 32));
      float l = 0.f;
      #pragma unroll
      for (int ni = 0; ni < MKV; ++ni)
        #pragma unroll
        for (int r = 0; r < 4; ++r) {
          float p = __expf(s[ni][r] - mx);
          s[ni][r] = p; l += p;
        }
      l += __shfl_xor(l, 16);
      l += __shfl_xor(l, 32);
      const float rs = 1.f / l;
      // ---- pack P rows (bf16 pairs); tiles beyond MKV are zero
      unsigned int plo[2*PCH], phi[2*PCH];
      #pragma unroll
      for (int ni = 0; ni < 2*PCH; ++ni) {
        if (ni < MKV) {
          plo[ni] = pk2(s[ni][0]*rs, s[ni][1]*rs);
          phi[ni] = pk2(s[ni][2]*rs, s[ni][3]*rs);
        } else { plo[ni] = 0u; phi[ni] = 0u; }
      }
      // ---- build B-fragments of P in-register (shfl dance)
      PF pf[PCH];
      #pragma unroll
      for (int kc = 0; kc < PCH; ++kc) {
        #pragma unroll
        for (int w = 0; w < 4; ++w) {
          const int srcLane = ln + 16*((qd & 1)*2 + (w >> 1));
          int va, vb;
          if (w & 1) {
            va = __shfl((int)phi[2*kc  ], srcLane, 64);
            vb = __shfl((int)phi[2*kc+1], srcLane, 64);
          } else {
            va = __shfl((int)plo[2*kc  ], srcLane, 64);
            vb = __shfl((int)plo[2*kc+1], srcLane, 64);
          }
          pf[kc].u[w] = (qd < 2) ? (unsigned int)va : (unsigned int)vb;
        }
      }
      // ---- out^T += Vtilde^T @ P^T
      #pragma unroll
      for (int oi = 0; oi < MO; ++oi) {
        const short* ap = Z3 + (oi*16 + ln)*VTS;
        f32x4 acc = accO[oi];
        #pragma unroll
        for (int kc = 0; kc < PCH; ++kc) {
          short8 af = *(const short8*)(ap + ((qd*8 + kc*32) ^ msk));
          acc = __builtin_amdgcn_mfma_f32_16x16x32_bf16(af, pf[kc].s, acc, 0,0,0);
        }
        accO[oi] = acc;
      }
    }
  }

  // out^T layout: lane q = wave*16+ln, col = oi*16+qd*4+r
  if (wave < MQ) {
    const int q = wave*16 + ln;
    #pragma unroll
    for (int oi = 0; oi < MO; ++oi) {
      #pragma unroll
      for (int r = 0; r < 4; ++r) {
        const int col = oi*16 + qd*4 + r;
        if (q < QROWS && col < OUTD) {
          float v = accO[oi][r];
          if (plain) {
            if (A) o2[bb + (long)q*TT + col] = v;   // [c][t]
            else   o1[bb + (long)q*CC + col] = v;   // [t][c]
          } else {
            long off = A ? ((long)q*TT + col) : ((long)col*TT + q);
            atomicAdd(&comb_g[bb + off], v);
          }
        }
      }
    }
  }
}

// ---------------------------------------------------------------- k_attn
// LDS = max(45056, 53248) = 53,248 B; natural VGPR (no min-occupancy cap).
__global__ __launch_bounds__(512) void k_attn(
    const bf16* __restrict__ spT_all, const bf16* __restrict__ tp_all,
    const bf16* __restrict__ wsec,
    const float* __restrict__ st_bq, const float* __restrict__ ts_bq,
    float* __restrict__ o1, float* __restrict__ o2,
    float* __restrict__ comb_g, int plain)
{
  __shared__ __align__(16) short SMEM[26624];
  if (blockIdx.x & 1)
    attn_body<1>(SMEM,spT_all,tp_all,wsec,st_bq,ts_bq,o1,o2,comb_g,plain);
  else
    attn_body<0>(SMEM,spT_all,tp_all,wsec,st_bq,ts_bq,o1,o2,comb_g,plain);
}

// ---------------------------------------------------------------- k_epi
__global__ __launch_bounds__(256) void k_epi(
    const float* __restrict__ comb_g,
    const float* __restrict__ c1, const float* __restrict__ c2,
    const float* __restrict__ x,
    const float* __restrict__ bias2,
    const float* __restrict__ alpha, const float* __restrict__ beta,
    const float* __restrict__ fcw, const float* __restrict__ fcb,
    float* __restrict__ out, int plain)
{
  __shared__ float s_cb[CC*CPAD];
  __shared__ float s_w[TT*TT];
  const int b = blockIdx.x, tid = threadIdx.x;
  const long bb = (long)b * (CC*TT);

  for (int o = tid; o < CC*TT; o += 256) {
    int c = o / TT, t = o - c*TT;
    float v;
    if (plain) v = c1[bb + (long)t*CC + c] + c2[bb + o];
    else       v = comb_g[bb + o];
    s_cb[c*CPAD + t] = v + bias2[c] + bias2[128 + t];
  }
  for (int o = tid; o < TT*TT; o += 256) {
    int f = o / TT, t = o - f*TT;
    s_w[t*TT + f] = fcw[o];
  }
  __syncthreads();
  if (tid < 2*TT) {
    const int t = tid >> 1, hf = tid & 1;
    float part = 0.f;
    for (int c = hf; c < CC; c += 2) part += s_cb[c*CPAD + t];
    float mean = (part + __shfl_xor(part, 1)) * (1.f/CC);
    float vp = 0.f;
    for (int c = hf; c < CC; c += 2) { float dv = s_cb[c*CPAD + t] - mean; vp += dv*dv; }
    float var = (vp + __shfl_xor(vp, 1)) * (1.f/CC);
    float rstd = 1.f / sqrtf(var + 1e-5f);
    for (int c = hf; c < CC; c += 2) {
      float y = (s_cb[c*CPAD + t] - mean) * rstd * alpha[c] + beta[c];
      s_cb[c*CPAD + t] = y + x[bb + c*TT + t];
    }
  }
  __syncthreads();
  for (int o = tid; o < CC*TT; o += 256) {
    int c = o / TT, f = o - c*TT;
    const float* cr = s_cb + c*CPAD;
    float a0 = 0.f, a1 = 0.f;
    for (int t = 0; t < TT; t += 2) {
      a0 += cr[t    ] * s_w[(t    )*TT + f];
      a1 += cr[t + 1] * s_w[(t + 1)*TT + f];
    }
    out[bb + o] = tanhf(a0 + a1 + fcb[f]);
  }
}

// ---------------------------------------------------------------- R4 fallback
__global__ __launch_bounds__(128) void k_fused(
    const float* __restrict__ x, const float* __restrict__ adj,
    const float* __restrict__ sadj, const float* __restrict__ tmask,
    const float* __restrict__ tadj,
    const float* __restrict__ st_wq, const float* __restrict__ st_bq,
    const float* __restrict__ st_wk, const float* __restrict__ st_bk,
    const float* __restrict__ st_wv, const float* __restrict__ st_bv,
    const float* __restrict__ st_wo, const float* __restrict__ st_bo,
    const float* __restrict__ ts_wq, const float* __restrict__ ts_bq,
    const float* __restrict__ ts_wk, const float* __restrict__ ts_bk,
    const float* __restrict__ ts_wv, const float* __restrict__ ts_bv,
    const float* __restrict__ ts_wo, const float* __restrict__ ts_bo,
    const float* __restrict__ alpha, const float* __restrict__ beta,
    const float* __restrict__ fcw, const float* __restrict__ fcb,
    float* __restrict__ out)
{
  __shared__ float s_sp[CC*TT];
  __shared__ float s_tp[CC*TT];
  __shared__ __align__(16) float s_kv[2*TT*HD];
  __shared__ float s_comb[CC*CPAD];
  __shared__ float s_A[JJ*JJ];
  __shared__ float s_dis[JJ];

  const int b = blockIdx.x, tid = threadIdx.x;
  const long bb = (long)b * (CC*TT);
  float* s_xs = s_comb;
  float* s_Mt = s_kv;

  if (tid < JJ) {
    float dsum = 0.f;
    for (int i = 0; i < JJ; ++i) dsum += adj[tid*JJ + i];
    s_dis[tid] = dsum > 0.f ? rsqrtf(dsum) : 0.f;
  }
  for (int o = tid; o < CC*TT; o += 128) s_xs[o] = x[bb + o];
  for (int o = tid; o < TT*TT; o += 128) {
    int f = o / TT, t = o - f*TT;
    s_Mt[t*TT + f] = tadj[o] * tmask[o];
  }
  __syncthreads();
  for (int o = tid; o < JJ*JJ; o += 128) {
    int v = o / JJ, j = o - v*JJ;
    s_A[o] = sadj[o] * adj[o] * s_dis[v] * s_dis[j];
  }
  __syncthreads();

  for (int o = tid; o < CC*TT; o += 128) {
    int c = o / TT, t = o - c*TT, v = c / 3, dd = c - v*3;
    float acc = 0.f;
    for (int j = 0; j < JJ; ++j) acc += s_A[v*JJ + j] * s_xs[(j*3 + dd)*TT + t];
    s_sp[o] = acc;
  }
  for (int o = tid; o < CC*TT; o += 128) {
    int n = o / TT, f = o - n*TT;
    float a0 = 0.f, a1 = 0.f;
    for (int t = 0; t < TT; t += 2) {
      a0 += s_xs[n*TT + t    ] * s_Mt[(t    )*TT + f];
      a1 += s_xs[n*TT + t + 1] * s_Mt[(t + 1)*TT + f];
    }
    s_tp[o] = a0 + a1;
  }
  __syncthreads();

  for (int o = tid; o < CC*TT; o += 128) {
    int c = o / TT, t = o - c*TT;
    s_comb[c*CPAD + t] = st_bo[c] + ts_bo[t];
  }

  {
    float* s_k = s_kv;
    float* s_v = s_kv + TT*HD;
    for (int h = 0; h < HH; ++h) {
      const int base = h*HD;
      __syncthreads();
      {
        const int d = tid & 63, krow = tid >> 6;
        for (int kk = 0; kk < CC/2; ++kk) {
          int k = kk*2 + krow;
          float aK = st_bk[base + d], aV = st_bv[base + d];
          const float* tr = s_tp + k*TT;
          for (int t = 0; t < TT; ++t) {
            float a = tr[t];
            aK += a * st_wk[(long)t*EE + base + d];
            aV += a * st_wv[(long)t*EE + base + d];
          }
          s_k[k*HD + d] = aK;
          s_v[k*HD + d] = aV;
        }
      }
      __syncthreads();
      if (tid < TT) {
        const int q = tid;
        float qv[HD];
        #pragma unroll
        for (int d = 0; d < HD; ++d) qv[d] = st_bq[base + d];
        for (int c = 0; c < CC; ++c) {
          float a = s_sp[c*TT + q];
          const float* wr = st_wq + (long)c*EE + base;
          #pragma unroll
          for (int d = 0; d < HD; ++d) qv[d] += a * wr[d];
        }
        float m = -INFINITY, l = 0.f, ov[HD];
        #pragma unroll
        for (int d = 0; d < HD; ++d) ov[d] = 0.f;
        for (int k = 0; k < CC; ++k) {
          const float4* kr4 = (const float4*)(s_k + k*HD);
          float s0=0.f,s1=0.f,s2=0.f,s3=0.f;
          #pragma unroll
          for (int i = 0; i < 16; ++i) {
            float4 kk4 = kr4[i];
            s0 += qv[4*i  ]*kk4.x; s1 += qv[4*i+1]*kk4.y;
            s2 += qv[4*i+2]*kk4.z; s3 += qv[4*i+3]*kk4.w;
          }
          float s  = (s0+s1+s2+s3) * 0.125f;
          float mn = fmaxf(m, s);
          float corr = __expf(m - mn);
          float p    = __expf(s - mn);
          l = l*corr + p;
          const float4* vr4 = (const float4*)(s_v + k*HD);
          #pragma unroll
          for (int i = 0; i < 16; ++i) {
            float4 vv4 = vr4[i];
            ov[4*i  ] = ov[4*i  ]*corr + p*vv4.x;
            ov[4*i+1] = ov[4*i+1]*corr + p*vv4.y;
            ov[4*i+2] = ov[4*i+2]*corr + p*vv4.z;
            ov[4*i+3] = ov[4*i+3]*corr + p*vv4.w;
          }
          m = mn;
        }
        float rl = 1.f/l;
        #pragma unroll
        for (int d = 0; d < HD; ++d) ov[d] *= rl;
        for (int c = 0; c < CC; ++c) {
          const float* wr = st_wo + (long)base*CC + c;
          float a0=0.f,a1=0.f,a2=0.f,a3=0.f;
          #pragma unroll
          for (int d = 0; d < HD; d += 4) {
            a0 += ov[d  ]*wr[(long)(d  )*CC]; a1 += ov[d+1]*wr[(long)(d+1)*CC];
            a2 += ov[d+2]*wr[(long)(d+2)*CC]; a3 += ov[d+3]*wr[(long)(d+3)*CC];
          }
          s_comb[c*CPAD + q] += a0+a1+a2+a3;
        }
      }
    }
  }

  {
    float* s_k = s_kv;
    float* s_v = s_kv + TT*HD;
    for (int h = 0; h < HH; ++h) {
      const int base = h*HD;
      __syncthreads();
      {
        const int d = tid & 63, krow = tid >> 6;
        for (int kk = 0; kk < TT/2; ++kk) {
          int k = kk*2 + krow;
          float aK = ts_bk[base + d], aV = ts_bv[base + d];
          for (int c = 0; c < CC; ++c) {
            float a = s_sp[c*TT + k];
            aK += a * ts_wk[(long)c*EE + base + d];
            aV += a * ts_wv[(long)c*EE + base + d];
          }
          s_k[k*HD + d] = aK;
          s_v[k*HD + d] = aV;
        }
      }
      __syncthreads();
      if (tid < CC) {
        const int q = tid;
        float qv[HD];
        #pragma unroll
        for (int d = 0; d < HD; ++d) qv[d] = ts_bq[base + d];
        const float* tr = s_tp + q*TT;
        for (int t = 0; t < TT; ++t) {
          float a = tr[t];
          const float* wr = ts_wq + (long)t*EE + base;
          #pragma unroll
          for (int d = 0; d < HD; ++d) qv[d] += a * wr[d];
        }
        float m = -INFINITY, l = 0.f, ov[HD];
        #pragma unroll
        for (int d = 0; d < HD; ++d) ov[d] = 0.f;
        for (int k = 0; k < TT; ++k) {
          const float4* kr4 = (const float4*)(s_k + k*HD);
          float s0=0.f,s1=0.f,s2=0.f,s3=0.f;
          #pragma unroll
          for (int i = 0; i < 16; ++i) {
            float4 kk4 = kr4[i];
            s0 += qv[4*i  ]*kk4.x; s1 += qv[4*i+1]*kk4.y;
            s2 += qv[4*i+2]*kk4.z; s3 += qv[4*i+3]*kk4.w;
          }
          float s  = (s0+s1+s2+s3) * 0.125f;
          float mn = fmaxf(m, s);
          float corr = __expf(m - mn);
          float p    = __expf(s - mn);
          l = l*corr + p;
          const float4* vr4 = (const float4*)(s_v + k*HD);
          #pragma unroll
          for (int i = 0; i < 16; ++i) {
            float4 vv4 = vr4[i];
            ov[4*i  ] = ov[4*i  ]*corr + p*vv4.x;
            ov[4*i+1] = ov[4*i+1]*corr + p*vv4.y;
            ov[4*i+2] = ov[4*i+2]*corr + p*vv4.z;
            ov[4*i+3] = ov[4*i+3]*corr + p*vv4.w;
          }
          m = mn;
        }
        float rl = 1.f/l;
        #pragma unroll
        for (int d = 0; d < HD; ++d) ov[d] *= rl;
        for (int t = 0; t < TT; ++t) {
          const float* wr = ts_wo + (long)base*TT + t;
          float a0=0.f,a1=0.f,a2=0.f,a3=0.f;
          #pragma unroll
          for (int d = 0; d < HD; d += 4) {
            a0 += ov[d  ]*wr[(long)(d  )*TT]; a1 += ov[d+1]*wr[(long)(d+1)*TT];
            a2 += ov[d+2]*wr[(long)(d+2)*TT]; a3 += ov[d+3]*wr[(long)(d+3)*TT];
          }
          s_comb[q*CPAD + t] += a0+a1+a2+a3;
        }
      }
    }
  }
  __syncthreads();

  if (tid < TT) {
    const int t = tid;
    float mean = 0.f;
    for (int c = 0; c < CC; ++c) mean += s_comb[c*CPAD + t];
    mean *= (1.f/CC);
    float var = 0.f;
    for (int c = 0; c < CC; ++c) { float dv = s_comb[c*CPAD + t] - mean; var += dv*dv; }
    var *= (1.f/CC);
    float rstd = 1.f / sqrtf(var + 1e-5f);
    for (int c = 0; c < CC; ++c) {
      float y = (s_comb[c*CPAD + t] - mean) * rstd * alpha[c] + beta[c];
      s_comb[c*CPAD + t] = y + x[bb + c*TT + t];
    }
  }
  __syncthreads();

  float* s_w = s_kv;
  for (int o = tid; o < TT*TT; o += 128) {
    int f = o / TT, t = o - f*TT;
    s_w[t*TT + f] = fcw[o];
  }
  __syncthreads();

  for (int o = tid; o < CC*TT; o += 128) {
    int c = o / TT, f = o - c*TT;
    const float* cr = s_comb + c*CPAD;
    float a0 = 0.f, a1 = 0.f;
    for (int t = 0; t < TT; t += 2) {
      a0 += cr[t    ] * s_w[(t    )*TT + f];
      a1 += cr[t + 1] * s_w[(t + 1)*TT + f];
    }
    out[bb + o] = tanhf(a0 + a1 + fcb[f]);
  }
}

// ---------------------------------------------------------------- launch
extern "C" void kernel_launch(void* const* d_in, const int* in_sizes, int n_in,
                              void* d_out, int out_size, void* d_ws, size_t ws_size,
                              hipStream_t stream) {
  const float* x     = (const float*)d_in[0];
  const float* adj   = (const float*)d_in[1];
  const float* sadj  = (const float*)d_in[2];
  const float* tmask = (const float*)d_in[3];
  const float* tadj  = (const float*)d_in[4];
  const float* st_wq = (const float*)d_in[5];  const float* st_bq = (const float*)d_in[6];
  const float* st_wk = (const float*)d_in[7];  const float* st_bk = (const float*)d_in[8];
  const float* st_wv = (const float*)d_in[9];  const float* st_bv = (const float*)d_in[10];
  const float* st_wo = (const float*)d_in[11]; const float* st_bo = (const float*)d_in[12];
  const float* ts_wq = (const float*)d_in[13]; const float* ts_bq = (const float*)d_in[14];
  const float* ts_wk = (const float*)d_in[15]; const float* ts_bk = (const float*)d_in[16];
  const float* ts_wv = (const float*)d_in[17]; const float* ts_bv = (const float*)d_in[18];
  const float* ts_wo = (const float*)d_in[19]; const float* ts_bo = (const float*)d_in[20];
  const float* alpha = (const float*)d_in[21]; const float* beta  = (const float*)d_in[22];
  const float* fcw   = (const float*)d_in[23]; const float* fcb   = (const float*)d_in[24];
  float* out = (float*)d_out;

  const int B = in_sizes[0] / (CC*TT);
  const size_t comb_bytes = (size_t)B * CC * TT * 4;
  const size_t w_bytes    = (size_t)W_TOTAL * 2 + 1024;   // + bias2 floats
  const size_t spt_bytes  = (size_t)B * SPT_R * SPT_S * 2;
  const size_t tp_bytes   = (size_t)B * TP_R * TP_S * 2;
  const size_t need_plain  = 2*comb_bytes + w_bytes + spt_bytes + tp_bytes;
  const size_t need_atomic =   comb_bytes + w_bytes + spt_bytes + tp_bytes;

  if (ws_size >= need_atomic) {
    const int plain = (ws_size >= need_plain) ? 1 : 0;
    const size_t cbuf = plain ? 2*comb_bytes : comb_bytes;
    float* c1      = (float*)d_ws;                       // plain: [B][T][C]; atomic: comb
    float* c2      = plain ? (float*)((char*)d_ws + comb_bytes) : nullptr;  // [B][C][T]
    bf16*  wsec    = (bf16*)((char*)d_ws + cbuf);
    float* bias2   = (float*)((char*)d_ws + cbuf + (size_t)W_TOTAL*2);
    bf16*  spT_all = (bf16*)((char*)d_ws + cbuf + w_bytes);
    bf16*  tp_all  = spT_all + (size_t)B * SPT_R * SPT_S;

    if (!plain) hipMemsetAsync(c1, 0, comb_bytes, stream);
    k_wprep<<<1553, 256, 0, stream>>>(st_wk, st_wq, ts_wk, ts_wq,
                                      st_wv, st_wo, ts_wv, ts_wo,
                                      st_bo, st_bv, ts_bo, ts_bv,
                                      wsec, bias2);
    k_prep<<<B, 256, 0, stream>>>(x, adj, sadj, tmask, tadj, spT_all, tp_all);
    k_attn<<<B*2, 512, 0, stream>>>(spT_all, tp_all, wsec, st_bq, ts_bq,
                                    plain ? c1 : nullptr, c2,
                                    plain ? nullptr : c1, plain);
    k_epi<<<B, 256, 0, stream>>>(plain ? nullptr : c1, c1, c2, x, bias2,
                                 alpha, beta, fcw, fcb, out, plain);
  } else {
    k_fused<<<B, 128, 0, stream>>>(x, adj, sadj, tmask, tadj,
                                   st_wq, st_bq, st_wk, st_bk, st_wv, st_bv, st_wo, st_bo,
                                   ts_wq, ts_bq, ts_wk, ts_bk, ts_wv, ts_bv, ts_wo, ts_bo,
                                   alpha, beta, fcw, fcb, out);
  }
}

// Round 6
// 675.169 us; speedup vs baseline: 3.1687x; 1.4363x over previous
//
#include <hip/hip_runtime.h>
#include <hip/hip_bf16.h>
#include <math.h>
#include <stdint.h>

typedef __hip_bfloat16 bf16;
typedef __attribute__((ext_vector_type(8))) short short8;
typedef __attribute__((ext_vector_type(4))) short short4v;
typedef __attribute__((ext_vector_type(4))) float f32x4;
typedef __attribute__((ext_vector_type(4))) unsigned int uint4v;
union PF { uint4v u; short8 s; };

#define CC 66      // channels = J*DIMS
#define TT 100     // time steps
#define JJ 22      // joints
#define HH 8       // heads
#define HD 64      // head dim
#define EE 512     // embed
#define CPAD 101   // comb stride (floats)

// global token layouts in ws (zero-padded)
#define SPT_R 112  // spT rows
#define SPT_S 96   // spT stride
#define TP_R 80    // tp rows
#define TP_S 128   // tp stride

// weight section offsets (bf16 elements) inside ws
#define W_STWK 0                    // [512][128]
#define W_STWQ 65536                // [512][96]
#define W_TSWK 114688               // [512][96]
#define W_TSWQ 163840               // [512][128]
#define W_VST  229376               // WtildeT st: [8][80][128]
#define W_VTS  311296               // WtildeT ts: [8][112][96]
#define W_TOTAL 397312

// k_attn2 LDS layout (short offsets)
#define TOKSP 0        // [112][104]
#define TOKTP 11648    // [80][136]
#define G0Z1  22528    // K  A0 [80][64]
#define G0Z2  27648    // Q  A0 [112][64]
#define G0Z3  34816    // VT A0 [80][128]
#define G1Z1  45056    // K  A1 [112][64]
#define G1Z2  52224    // Q  A1 [80][64]
#define G1Z3  57344    // VT A1 [112][128]
#define SMEM_SH 71680  // 143,360 B

__device__ __forceinline__ bf16 f2b(float v){ return __float2bfloat16(v); }
__device__ __forceinline__ short sb(float v){ __hip_bfloat16 h = __float2bfloat16(v); return *(short*)&h; }
__device__ __forceinline__ unsigned int pk2(float a, float b){
  unsigned short ua = (unsigned short)sb(a), ub = (unsigned short)sb(b);
  return (unsigned int)ua | ((unsigned int)ub << 16);
}

// ---------------------------------------------------------------- k_wprep
__device__ __forceinline__ void tr_body(
    const float* __restrict__ src, bf16* __restrict__ dst,
    int Rsrc, int Csrc, int JP, int IP, int blk, int tid)
{
  int o = blk*256 + tid;
  if (o >= JP*IP) return;
  int j = o / IP, i = o - j*IP;
  float v = (j < Csrc && i < Rsrc) ? src[(long)i*Csrc + j] : 0.f;
  dst[o] = f2b(v);
}

__device__ __forceinline__ void wt_body(
    const float* __restrict__ wv, const float* __restrict__ wo,
    bf16* __restrict__ dst, int OUT, int KDIM, int OP, int KP, int blk, int tid)
{
  int idx = blk*256 + tid;
  if (idx >= 8*OP*KP) return;
  int o = idx % OP;
  int hk = idx / OP;
  int k = hk % KP, h = hk / KP;
  float acc = 0.f;
  if (o < OUT && k < KDIM) {
    const float* wvp = wv + (long)k*EE + h*64;
    const float* wop = wo + (long)(h*64)*OUT + o;
    #pragma unroll 8
    for (int d = 0; d < 64; ++d) acc += wvp[d] * wop[(long)d*OUT];
  }
  dst[(long)h*OP*KP + (long)o*KP + k] = f2b(acc);
}

__global__ __launch_bounds__(256) void k_wprep(
    const float* __restrict__ st_wk, const float* __restrict__ st_wq,
    const float* __restrict__ ts_wk, const float* __restrict__ ts_wq,
    const float* __restrict__ st_wv, const float* __restrict__ st_wo,
    const float* __restrict__ ts_wv, const float* __restrict__ ts_wo,
    const float* __restrict__ st_bo, const float* __restrict__ st_bv,
    const float* __restrict__ ts_bo, const float* __restrict__ ts_bv,
    bf16* __restrict__ wsec, float* __restrict__ bias2)
{
  const int blk = blockIdx.x, tid = threadIdx.x;
  if      (blk <  256) tr_body(st_wk, wsec + W_STWK, TT, EE, EE, 128, blk,      tid);
  else if (blk <  448) tr_body(st_wq, wsec + W_STWQ, CC, EE, EE,  96, blk-256,  tid);
  else if (blk <  640) tr_body(ts_wk, wsec + W_TSWK, CC, EE, EE,  96, blk-448,  tid);
  else if (blk <  896) tr_body(ts_wq, wsec + W_TSWQ, TT, EE, EE, 128, blk-640,  tid);
  else if (blk < 1216) wt_body(st_wv, st_wo, wsec + W_VST, CC, TT,  80, 128, blk-896,  tid);
  else if (blk < 1552) wt_body(ts_wv, ts_wo, wsec + W_VTS, TT, CC, 112,  96, blk-1216, tid);
  else {
    if (tid < 128) {
      int c = tid; float a = 0.f;
      if (c < CC) {
        a = st_bo[c];
        for (int e = 0; e < EE; ++e) a += st_bv[e] * st_wo[(long)e*CC + c];
      }
      bias2[tid] = a;
    } else {
      int t = tid - 128; float a = 0.f;
      if (t < TT) {
        a = ts_bo[t];
        for (int e = 0; e < EE; ++e) a += ts_bv[e] * ts_wo[(long)e*TT + t];
      }
      bias2[tid] = a;
    }
  }
}

// ---------------------------------------------------------------- k_prep
__global__ __launch_bounds__(256) void k_prep(
    const float* __restrict__ x, const float* __restrict__ adj,
    const float* __restrict__ sadj, const float* __restrict__ tmask,
    const float* __restrict__ tadj,
    bf16* __restrict__ spT_all, bf16* __restrict__ tp_all)
{
  __shared__ float s_x[CC*TT];
  __shared__ float s_Mt[TT*TT];
  __shared__ float s_A[JJ*JJ];
  __shared__ float s_dis[JJ];
  const int b = blockIdx.x, tid = threadIdx.x;
  const long bb = (long)b * (CC*TT);

  if (tid < JJ) {
    float dsum = 0.f;
    for (int i = 0; i < JJ; ++i) dsum += adj[tid*JJ + i];
    s_dis[tid] = dsum > 0.f ? rsqrtf(dsum) : 0.f;
  }
  for (int o = tid; o < CC*TT; o += 256) s_x[o] = x[bb + o];
  for (int o = tid; o < TT*TT; o += 256) {
    int f = o / TT, t = o - f*TT;
    s_Mt[t*TT + f] = tadj[o] * tmask[o];
  }
  __syncthreads();
  for (int o = tid; o < JJ*JJ; o += 256) {
    int v = o / JJ, j = o - v*JJ;
    s_A[o] = sadj[o] * adj[o] * s_dis[v] * s_dis[j];
  }
  __syncthreads();

  bf16* spT = spT_all + (long)b * (SPT_R*SPT_S);
  bf16* tp  = tp_all  + (long)b * (TP_R*TP_S);

  // spT[t][c], 4-t blocks with float4 x reads
  for (int o = tid; o < 28*SPT_S; o += 256) {
    int t4 = o / SPT_S, c = o - t4*SPT_S;
    int t = t4*4;
    float ax=0.f, ay=0.f, az=0.f, aw=0.f;
    if (t < TT && c < CC) {
      int v = c/3, dd = c - v*3;
      for (int j = 0; j < JJ; ++j) {
        float av = s_A[v*JJ + j];
        float4 xv = *(const float4*)(s_x + (j*3+dd)*TT + t);
        ax += av*xv.x; ay += av*xv.y; az += av*xv.z; aw += av*xv.w;
      }
    }
    spT[(t  )*SPT_S + c] = f2b(ax);
    spT[(t+1)*SPT_S + c] = f2b(ay);
    spT[(t+2)*SPT_S + c] = f2b(az);
    spT[(t+3)*SPT_S + c] = f2b(aw);
  }
  // tp[n][f], 4-f blocks with float4 Mt reads
  for (int o = tid; o < TP_R*32; o += 256) {
    int n = o >> 5, f4 = o & 31;
    int f = f4*4;
    float ax=0.f, ay=0.f, az=0.f, aw=0.f;
    if (n < CC && f < TT) {
      for (int t = 0; t < TT; ++t) {
        float xv = s_x[n*TT + t];
        float4 w = *(const float4*)(s_Mt + t*TT + f);
        ax += xv*w.x; ay += xv*w.y; az += xv*w.z; aw += xv*w.w;
      }
    }
    short4v pk;
    pk.x = sb(ax); pk.y = sb(ay); pk.z = sb(az); pk.w = sb(aw);
    *(short4v*)(tp + n*TP_S + f) = pk;
  }
}

// ---------------------------------------------------------------- build helpers
// Swapped-operand builds: m-dim = consumer's k-dim -> one ds_write_b64/tile.
// Tokens now come from LDS (staged once per block); weights stream from L2.
// K/Q: m = d (4 tiles), n = token rows; 2 waves per m-tile.
template<int Nt, int KCH, int SA, int SB>
__device__ __forceinline__ void build_kq(
    const short* __restrict__ W, const short* __restrict__ Tok,
    short* __restrict__ Z, const float* __restrict__ rowbias,
    int gw, int ln, int qd)
{
  const int mi = gw & 3;
  const int d0 = mi*16 + qd*4;
  const short* ap = W + (long)(mi*16 + ln)*SA;
  short8 af[KCH];
  #pragma unroll
  for (int kc = 0; kc < KCH; ++kc) af[kc] = *(const short8*)(ap + qd*8 + kc*32);
  float rb0=0.f, rb1=0.f, rb2=0.f, rb3=0.f;
  if (rowbias) { rb0=rowbias[d0]; rb1=rowbias[d0+1]; rb2=rowbias[d0+2]; rb3=rowbias[d0+3]; }
  constexpr int NU = (Nt + 1) / 2;
  #pragma unroll
  for (int u = 0; u < NU; ++u) {
    const int ni = (gw >> 2) + 2*u;
    if (ni < Nt) {
      const int row = ni*16 + ln;
      const short* bp = Tok + (long)row*SB;
      f32x4 acc = {0.f,0.f,0.f,0.f};
      #pragma unroll
      for (int kc = 0; kc < KCH; ++kc)
        acc = __builtin_amdgcn_mfma_f32_16x16x32_bf16(
            af[kc], *(const short8*)(bp + qd*8 + kc*32), acc, 0,0,0);
      short4v pk;
      pk.x = sb(acc[0]+rb0); pk.y = sb(acc[1]+rb1);
      pk.z = sb(acc[2]+rb2); pk.w = sb(acc[3]+rb3);
      *(short4v*)(Z + row*64 + (d0 ^ ((ln & 7) << 3))) = pk;
    }
  }
}

// VtildeT: m = kv (Mt tiles, wave-owned), n = out rows; token A-frags cached.
template<int Mt, int Nt, int KCH, int SA, int SB, int SZ>
__device__ __forceinline__ void build_vt(
    const short* __restrict__ Tok, const short* __restrict__ Wv,
    short* __restrict__ Z, int gw, int ln, int qd)
{
  if (gw >= Mt) return;
  const int mi = gw;
  const int k0 = mi*16 + qd*4;
  const short* ap = Tok + (long)(mi*16 + ln)*SA;
  short8 af[KCH];
  #pragma unroll
  for (int kc = 0; kc < KCH; ++kc) af[kc] = *(const short8*)(ap + qd*8 + kc*32);
  #pragma unroll
  for (int ni = 0; ni < Nt; ++ni) {
    const int row = ni*16 + ln;
    const short* bp = Wv + (long)row*SB;
    f32x4 acc = {0.f,0.f,0.f,0.f};
    #pragma unroll
    for (int kc = 0; kc < KCH; ++kc)
      acc = __builtin_amdgcn_mfma_f32_16x16x32_bf16(
          af[kc], *(const short8*)(bp + qd*8 + kc*32), acc, 0,0,0);
    short4v pk;
    pk.x = sb(acc[0]); pk.y = sb(acc[1]); pk.z = sb(acc[2]); pk.w = sb(acc[3]);
    *(short4v*)(Z + row*SZ + (k0 ^ ((ln & 7) << 3))) = pk;
  }
}

// ---------------------------------------------------------------- per-head pieces
template<int A>
__device__ __forceinline__ void build_head(
    short* __restrict__ SMEM, const short* __restrict__ wsec,
    const float* __restrict__ bq, int h, int gw, int ln, int qd)
{
  constexpr int MQ  = A ? 5 : 7;
  constexpr int MKV = A ? 7 : 5;
  constexpr int MO  = A ? 7 : 5;
  constexpr int QCH = A ? 4 : 3;
  constexpr int KCH = A ? 3 : 4;
  constexpr int SWQ = A ? 128 : 96;   // wq global stride
  constexpr int SWK = A ? 96 : 128;   // wk global stride
  constexpr int SWV = A ? 96 : 128;   // wvt global stride
  constexpr int STQ = A ? 136 : 104;  // q-token LDS stride
  constexpr int STK = A ? 104 : 136;  // kv-token LDS stride
  const short* tokq = SMEM + (A ? TOKTP : TOKSP);
  const short* tokk = SMEM + (A ? TOKSP : TOKTP);
  short* Z1 = SMEM + (A ? G1Z1 : G0Z1);
  short* Z2 = SMEM + (A ? G1Z2 : G0Z2);
  short* Z3 = SMEM + (A ? G1Z3 : G0Z3);
  const short* wkT = wsec + (A ? W_TSWK : W_STWK);
  const short* wqT = wsec + (A ? W_TSWQ : W_STWQ);
  const short* wvt = wsec + (A ? W_VTS  : W_VST);
  const int base = h * HD;
  build_kq<MKV, KCH, SWK, STK>(wkT + (long)base*SWK, tokk, Z1, nullptr, gw, ln, qd);
  build_kq<MQ,  QCH, SWQ, STQ>(wqT + (long)base*SWQ, tokq, Z2, bq + base, gw, ln, qd);
  build_vt<MKV, MO, KCH, STK, SWV, 128>(tokk, wvt + (long)h*(MO*16*SWV), Z3, gw, ln, qd);
}

template<int A>
__device__ __forceinline__ void chain_head(
    const short* __restrict__ SMEM, f32x4* __restrict__ accO,
    int gw, int ln, int qd)
{
  constexpr int KVR = A ? 100 : 66;
  constexpr int MQ  = A ? 5 : 7;
  constexpr int MKV = A ? 7 : 5;
  constexpr int MO  = A ? 7 : 5;
  constexpr int PCH = A ? 4 : 3;
  if (gw >= MQ) return;
  const short* Z1 = SMEM + (A ? G1Z1 : G0Z1);
  const short* Z2 = SMEM + (A ? G1Z2 : G0Z2);
  const short* Z3 = SMEM + (A ? G1Z3 : G0Z3);
  const int msk = (ln & 7) << 3;

  // S^T = K @ Q^T : lane holds q=ln, kv = ni*16+qd*4+r
  const short* bqp = Z2 + (gw*16 + ln)*64;
  const short8 qf0 = *(const short8*)(bqp + ((qd*8     ) ^ msk));
  const short8 qf1 = *(const short8*)(bqp + ((qd*8 + 32) ^ msk));
  f32x4 s[MKV];
  #pragma unroll
  for (int ni = 0; ni < MKV; ++ni) {
    const short* ap = Z1 + (ni*16 + ln)*64;
    f32x4 acc = {0.f,0.f,0.f,0.f};
    acc = __builtin_amdgcn_mfma_f32_16x16x32_bf16(
        *(const short8*)(ap + ((qd*8     ) ^ msk)), qf0, acc, 0,0,0);
    acc = __builtin_amdgcn_mfma_f32_16x16x32_bf16(
        *(const short8*)(ap + ((qd*8 + 32) ^ msk)), qf1, acc, 0,0,0);
    s[ni] = acc;
  }
  // mask pad kv + scale
  #pragma unroll
  for (int ni = 0; ni < MKV; ++ni) {
    #pragma unroll
    for (int r = 0; r < 4; ++r) {
      const int kv = ni*16 + qd*4 + r;
      s[ni][r] = (kv < KVR) ? s[ni][r]*0.125f : -1e30f;
    }
  }
  // softmax over kv (own regs + shfl_xor 16, 32)
  float mx = -1e30f;
  #pragma unroll
  for (int ni = 0; ni < MKV; ++ni)
    #pragma unroll
    for (int r = 0; r < 4; ++r) mx = fmaxf(mx, s[ni][r]);
  mx = fmaxf(mx, __shfl_xor(mx, 16));
  mx = fmaxf(mx, __shfl_xor(mx, 32));
  float l = 0.f;
  #pragma unroll
  for (int ni = 0; ni < MKV; ++ni)
    #pragma unroll
    for (int r = 0; r < 4; ++r) {
      float p = __expf(s[ni][r] - mx);
      s[ni][r] = p; l += p;
    }
  l += __shfl_xor(l, 16);
  l += __shfl_xor(l, 32);
  const float rs = 1.f / l;
  // pack P rows (bf16 pairs); tiles beyond MKV are zero
  unsigned int plo[2*PCH], phi[2*PCH];
  #pragma unroll
  for (int ni = 0; ni < 2*PCH; ++ni) {
    if (ni < MKV) {
      plo[ni] = pk2(s[ni][0]*rs, s[ni][1]*rs);
      phi[ni] = pk2(s[ni][2]*rs, s[ni][3]*rs);
    } else { plo[ni] = 0u; phi[ni] = 0u; }
  }
  // build B-fragments of P in-register (shfl dance)
  PF pf[PCH];
  #pragma unroll
  for (int kc = 0; kc < PCH; ++kc) {
    #pragma unroll
    for (int w = 0; w < 4; ++w) {
      const int srcLane = ln + 16*((qd & 1)*2 + (w >> 1));
      int va, vb;
      if (w & 1) {
        va = __shfl((int)phi[2*kc  ], srcLane, 64);
        vb = __shfl((int)phi[2*kc+1], srcLane, 64);
      } else {
        va = __shfl((int)plo[2*kc  ], srcLane, 64);
        vb = __shfl((int)plo[2*kc+1], srcLane, 64);
      }
      pf[kc].u[w] = (qd < 2) ? (unsigned int)va : (unsigned int)vb;
    }
  }
  // out^T += Vtilde^T @ P^T
  #pragma unroll
  for (int oi = 0; oi < MO; ++oi) {
    const short* ap = Z3 + (oi*16 + ln)*128;
    f32x4 acc = accO[oi];
    #pragma unroll
    for (int kc = 0; kc < PCH; ++kc) {
      short8 af = *(const short8*)(ap + ((qd*8 + kc*32) ^ msk));
      acc = __builtin_amdgcn_mfma_f32_16x16x32_bf16(af, pf[kc].s, acc, 0,0,0);
    }
    accO[oi] = acc;
  }
}

// ---------------------------------------------------------------- k_attn2 (mega)
// 1024 threads: waves 0-7 flavor A=0, waves 8-15 A=1. Tokens staged in LDS
// once, reused across all 8 heads by both flavors. Epilogue (LN + FC + tanh)
// fused in, using the dead zone space for comb + fcw^T.
__global__ __launch_bounds__(1024) void k_attn2(
    const bf16* __restrict__ spT_all, const bf16* __restrict__ tp_all,
    const bf16* __restrict__ wsec_,
    const float* __restrict__ st_bq, const float* __restrict__ ts_bq,
    const float* __restrict__ bias2, const float* __restrict__ x,
    const float* __restrict__ alpha, const float* __restrict__ beta,
    const float* __restrict__ fcw, const float* __restrict__ fcb,
    float* __restrict__ out)
{
  __shared__ __align__(16) short SMEM[SMEM_SH];
  const int b = blockIdx.x, tid = threadIdx.x;
  const long bb = (long)b * (CC*TT);
  const int wave = tid >> 6, lane = tid & 63, ln = lane & 15, qd = lane >> 4;
  const int g = wave >> 3, gw = wave & 7;
  const short* wsec = (const short*)wsec_;

  // stage tokens -> LDS (padded strides 104/136 for bank spread)
  {
    const short* gsp = (const short*)(spT_all + (long)b*SPT_R*SPT_S);
    const short* gtp = (const short*)(tp_all  + (long)b*TP_R*TP_S);
    for (int o = tid; o < 112*12; o += 1024) {
      int r = o / 12, c8 = o - r*12;
      *(short8*)(SMEM + TOKSP + r*104 + c8*8) = *(const short8*)(gsp + r*SPT_S + c8*8);
    }
    for (int o = tid; o < 80*16; o += 1024) {
      int r = o >> 4, c8 = o & 15;
      *(short8*)(SMEM + TOKTP + r*136 + c8*8) = *(const short8*)(gtp + r*TP_S + c8*8);
    }
  }
  // Z3 pad kv-cols zero (builds never rewrite them; PV reads them as zeros)
  for (int o = tid; o < 80*16; o += 1024) {
    int r = o >> 4, kv = 80 + (o & 15);
    SMEM[G0Z3 + r*128 + (kv ^ ((r & 7) << 3))] = 0;
  }
  for (int o = tid; o < 112*16; o += 1024) {
    int r = o >> 4, kv = 112 + (o & 15);
    SMEM[G1Z3 + r*128 + (kv ^ ((r & 7) << 3))] = 0;
  }

  f32x4 accO[7];
  { f32x4 z = {0.f,0.f,0.f,0.f};
    #pragma unroll
    for (int i = 0; i < 7; ++i) accO[i] = z; }

  for (int h = 0; h < HH; ++h) {
    __syncthreads();   // staging/pads done (h=0); zone WAR (h>0)
    if (g == 0) build_head<0>(SMEM, wsec, st_bq, h, gw, ln, qd);
    else        build_head<1>(SMEM, wsec, ts_bq, h, gw, ln, qd);
    __syncthreads();
    if (g == 0) chain_head<0>(SMEM, accO, gw, ln, qd);
    else        chain_head<1>(SMEM, accO, gw, ln, qd);
  }

  // ---------------- fused epilogue (zones dead) ----------------
  float* comb = (float*)(SMEM + G0Z1);   // [66][101] floats = 26,664 B
  float* s_w  = comb + 6668;             // fcw^T [t][f], 40,000 B
  __syncthreads();
  // E1: G0 dumps accO (=); G1 stages fcw^T
  if (g == 0) {
    if (gw < 7) {
      const int t = gw*16 + ln;
      if (t < TT) {
        #pragma unroll
        for (int oi = 0; oi < 5; ++oi)
          #pragma unroll
          for (int r = 0; r < 4; ++r) {
            const int c = oi*16 + qd*4 + r;
            if (c < CC) comb[c*CPAD + t] = accO[oi][r];
          }
      }
    }
  } else {
    for (int o = tid - 512; o < TT*TT; o += 512) {
      int f = o / TT, t = o - f*TT;
      s_w[t*TT + f] = fcw[o];
    }
  }
  __syncthreads();
  // E2: G1 dumps accO (+=)
  if (g == 1 && gw < 5) {
    const int c = gw*16 + ln;
    if (c < CC) {
      #pragma unroll
      for (int oi = 0; oi < 7; ++oi)
        #pragma unroll
        for (int r = 0; r < 4; ++r) {
          const int t = oi*16 + qd*4 + r;
          if (t < TT) comb[c*CPAD + t] += accO[oi][r];
        }
    }
  }
  __syncthreads();
  // E3: folded output biases
  for (int o = tid; o < CC*TT; o += 1024) {
    int c = o / TT, t = o - c*TT;
    comb[c*CPAD + t] += bias2[c] + bias2[128 + t];
  }
  __syncthreads();
  // E4: LN over channels (2 lanes per t) + residual
  if (tid < 2*TT) {
    const int t = tid >> 1, hf = tid & 1;
    float part = 0.f;
    for (int c = hf; c < CC; c += 2) part += comb[c*CPAD + t];
    float mean = (part + __shfl_xor(part, 1)) * (1.f/CC);
    float vp = 0.f;
    for (int c = hf; c < CC; c += 2) { float dv = comb[c*CPAD + t] - mean; vp += dv*dv; }
    float var = (vp + __shfl_xor(vp, 1)) * (1.f/CC);
    float rstd = 1.f / sqrtf(var + 1e-5f);
    for (int c = hf; c < CC; c += 2) {
      float y = (comb[c*CPAD + t] - mean) * rstd * alpha[c] + beta[c];
      comb[c*CPAD + t] = y + x[bb + c*TT + t];
    }
  }
  __syncthreads();
  // E5: FC over t (float4 weights) + tanh -> out
  for (int o = tid; o < CC*25; o += 1024) {
    int c = o / 25, f4 = o - c*25;
    int f = f4*4;
    const float* cr = comb + c*CPAD;
    float ax=0.f, ay=0.f, az=0.f, aw=0.f;
    for (int t = 0; t < TT; ++t) {
      float xv = cr[t];
      float4 w = *(const float4*)(s_w + t*TT + f);
      ax += xv*w.x; ay += xv*w.y; az += xv*w.z; aw += xv*w.w;
    }
    float4 r4;
    r4.x = tanhf(ax + fcb[f  ]); r4.y = tanhf(ay + fcb[f+1]);
    r4.z = tanhf(az + fcb[f+2]); r4.w = tanhf(aw + fcb[f+3]);
    *(float4*)(out + bb + c*TT + f) = r4;
  }
}

// ---------------------------------------------------------------- R4 fallback
__global__ __launch_bounds__(128) void k_fused(
    const float* __restrict__ x, const float* __restrict__ adj,
    const float* __restrict__ sadj, const float* __restrict__ tmask,
    const float* __restrict__ tadj,
    const float* __restrict__ st_wq, const float* __restrict__ st_bq,
    const float* __restrict__ st_wk, const float* __restrict__ st_bk,
    const float* __restrict__ st_wv, const float* __restrict__ st_bv,
    const float* __restrict__ st_wo, const float* __restrict__ st_bo,
    const float* __restrict__ ts_wq, const float* __restrict__ ts_bq,
    const float* __restrict__ ts_wk, const float* __restrict__ ts_bk,
    const float* __restrict__ ts_wv, const float* __restrict__ ts_bv,
    const float* __restrict__ ts_wo, const float* __restrict__ ts_bo,
    const float* __restrict__ alpha, const float* __restrict__ beta,
    const float* __restrict__ fcw, const float* __restrict__ fcb,
    float* __restrict__ out)
{
  __shared__ float s_sp[CC*TT];
  __shared__ float s_tp[CC*TT];
  __shared__ __align__(16) float s_kv[2*TT*HD];
  __shared__ float s_comb[CC*CPAD];
  __shared__ float s_A[JJ*JJ];
  __shared__ float s_dis[JJ];

  const int b = blockIdx.x, tid = threadIdx.x;
  const long bb = (long)b * (CC*TT);
  float* s_xs = s_comb;
  float* s_Mt = s_kv;

  if (tid < JJ) {
    float dsum = 0.f;
    for (int i = 0; i < JJ; ++i) dsum += adj[tid*JJ + i];
    s_dis[tid] = dsum > 0.f ? rsqrtf(dsum) : 0.f;
  }
  for (int o = tid; o < CC*TT; o += 128) s_xs[o] = x[bb + o];
  for (int o = tid; o < TT*TT; o += 128) {
    int f = o / TT, t = o - f*TT;
    s_Mt[t*TT + f] = tadj[o] * tmask[o];
  }
  __syncthreads();
  for (int o = tid; o < JJ*JJ; o += 128) {
    int v = o / JJ, j = o - v*JJ;
    s_A[o] = sadj[o] * adj[o] * s_dis[v] * s_dis[j];
  }
  __syncthreads();

  for (int o = tid; o < CC*TT; o += 128) {
    int c = o / TT, t = o - c*TT, v = c / 3, dd = c - v*3;
    float acc = 0.f;
    for (int j = 0; j < JJ; ++j) acc += s_A[v*JJ + j] * s_xs[(j*3 + dd)*TT + t];
    s_sp[o] = acc;
  }
  for (int o = tid; o < CC*TT; o += 128) {
    int n = o / TT, f = o - n*TT;
    float a0 = 0.f, a1 = 0.f;
    for (int t = 0; t < TT; t += 2) {
      a0 += s_xs[n*TT + t    ] * s_Mt[(t    )*TT + f];
      a1 += s_xs[n*TT + t + 1] * s_Mt[(t + 1)*TT + f];
    }
    s_tp[o] = a0 + a1;
  }
  __syncthreads();

  for (int o = tid; o < CC*TT; o += 128) {
    int c = o / TT, t = o - c*TT;
    s_comb[c*CPAD + t] = st_bo[c] + ts_bo[t];
  }

  {
    float* s_k = s_kv;
    float* s_v = s_kv + TT*HD;
    for (int h = 0; h < HH; ++h) {
      const int base = h*HD;
      __syncthreads();
      {
        const int d = tid & 63, krow = tid >> 6;
        for (int kk = 0; kk < CC/2; ++kk) {
          int k = kk*2 + krow;
          float aK = st_bk[base + d], aV = st_bv[base + d];
          const float* tr = s_tp + k*TT;
          for (int t = 0; t < TT; ++t) {
            float a = tr[t];
            aK += a * st_wk[(long)t*EE + base + d];
            aV += a * st_wv[(long)t*EE + base + d];
          }
          s_k[k*HD + d] = aK;
          s_v[k*HD + d] = aV;
        }
      }
      __syncthreads();
      if (tid < TT) {
        const int q = tid;
        float qv[HD];
        #pragma unroll
        for (int d = 0; d < HD; ++d) qv[d] = st_bq[base + d];
        for (int c = 0; c < CC; ++c) {
          float a = s_sp[c*TT + q];
          const float* wr = st_wq + (long)c*EE + base;
          #pragma unroll
          for (int d = 0; d < HD; ++d) qv[d] += a * wr[d];
        }
        float m = -INFINITY, l = 0.f, ov[HD];
        #pragma unroll
        for (int d = 0; d < HD; ++d) ov[d] = 0.f;
        for (int k = 0; k < CC; ++k) {
          const float4* kr4 = (const float4*)(s_k + k*HD);
          float s0=0.f,s1=0.f,s2=0.f,s3=0.f;
          #pragma unroll
          for (int i = 0; i < 16; ++i) {
            float4 kk4 = kr4[i];
            s0 += qv[4*i  ]*kk4.x; s1 += qv[4*i+1]*kk4.y;
            s2 += qv[4*i+2]*kk4.z; s3 += qv[4*i+3]*kk4.w;
          }
          float s  = (s0+s1+s2+s3) * 0.125f;
          float mn = fmaxf(m, s);
          float corr = __expf(m - mn);
          float p    = __expf(s - mn);
          l = l*corr + p;
          const float4* vr4 = (const float4*)(s_v + k*HD);
          #pragma unroll
          for (int i = 0; i < 16; ++i) {
            float4 vv4 = vr4[i];
            ov[4*i  ] = ov[4*i  ]*corr + p*vv4.x;
            ov[4*i+1] = ov[4*i+1]*corr + p*vv4.y;
            ov[4*i+2] = ov[4*i+2]*corr + p*vv4.z;
            ov[4*i+3] = ov[4*i+3]*corr + p*vv4.w;
          }
          m = mn;
        }
        float rl = 1.f/l;
        #pragma unroll
        for (int d = 0; d < HD; ++d) ov[d] *= rl;
        for (int c = 0; c < CC; ++c) {
          const float* wr = st_wo + (long)base*CC + c;
          float a0=0.f,a1=0.f,a2=0.f,a3=0.f;
          #pragma unroll
          for (int d = 0; d < HD; d += 4) {
            a0 += ov[d  ]*wr[(long)(d  )*CC]; a1 += ov[d+1]*wr[(long)(d+1)*CC];
            a2 += ov[d+2]*wr[(long)(d+2)*CC]; a3 += ov[d+3]*wr[(long)(d+3)*CC];
          }
          s_comb[c*CPAD + q] += a0+a1+a2+a3;
        }
      }
    }
  }

  {
    float* s_k = s_kv;
    float* s_v = s_kv + TT*HD;
    for (int h = 0; h < HH; ++h) {
      const int base = h*HD;
      __syncthreads();
      {
        const int d = tid & 63, krow = tid >> 6;
        for (int kk = 0; kk < TT/2; ++kk) {
          int k = kk*2 + krow;
          float aK = ts_bk[base + d], aV = ts_bv[base + d];
          for (int c = 0; c < CC; ++c) {
            float a = s_sp[c*TT + k];
            aK += a * ts_wk[(long)c*EE + base + d];
            aV += a * ts_wv[(long)c*EE + base + d];
          }
          s_k[k*HD + d] = aK;
          s_v[k*HD + d] = aV;
        }
      }
      __syncthreads();
      if (tid < CC) {
        const int q = tid;
        float qv[HD];
        #pragma unroll
        for (int d = 0; d < HD; ++d) qv[d] = ts_bq[base + d];
        const float* tr = s_tp + q*TT;
        for (int t = 0; t < TT; ++t) {
          float a = tr[t];
          const float* wr = ts_wq + (long)t*EE + base;
          #pragma unroll
          for (int d = 0; d < HD; ++d) qv[d] += a * wr[d];
        }
        float m = -INFINITY, l = 0.f, ov[HD];
        #pragma unroll
        for (int d = 0; d < HD; ++d) ov[d] = 0.f;
        for (int k = 0; k < TT; ++k) {
          const float4* kr4 = (const float4*)(s_k + k*HD);
          float s0=0.f,s1=0.f,s2=0.f,s3=0.f;
          #pragma unroll
          for (int i = 0; i < 16; ++i) {
            float4 kk4 = kr4[i];
            s0 += qv[4*i  ]*kk4.x; s1 += qv[4*i+1]*kk4.y;
            s2 += qv[4*i+2]*kk4.z; s3 += qv[4*i+3]*kk4.w;
          }
          float s  = (s0+s1+s2+s3) * 0.125f;
          float mn = fmaxf(m, s);
          float corr = __expf(m - mn);
          float p    = __expf(s - mn);
          l = l*corr + p;
          const float4* vr4 = (const float4*)(s_v + k*HD);
          #pragma unroll
          for (int i = 0; i < 16; ++i) {
            float4 vv4 = vr4[i];
            ov[4*i  ] = ov[4*i  ]*corr + p*vv4.x;
            ov[4*i+1] = ov[4*i+1]*corr + p*vv4.y;
            ov[4*i+2] = ov[4*i+2]*corr + p*vv4.z;
            ov[4*i+3] = ov[4*i+3]*corr + p*vv4.w;
          }
          m = mn;
        }
        float rl = 1.f/l;
        #pragma unroll
        for (int d = 0; d < HD; ++d) ov[d] *= rl;
        for (int t = 0; t < TT; ++t) {
          const float* wr = ts_wo + (long)base*TT + t;
          float a0=0.f,a1=0.f,a2=0.f,a3=0.f;
          #pragma unroll
          for (int d = 0; d < HD; d += 4) {
            a0 += ov[d  ]*wr[(long)(d  )*TT]; a1 += ov[d+1]*wr[(long)(d+1)*TT];
            a2 += ov[d+2]*wr[(long)(d+2)*TT]; a3 += ov[d+3]*wr[(long)(d+3)*TT];
          }
          s_comb[q*CPAD + t] += a0+a1+a2+a3;
        }
      }
    }
  }
  __syncthreads();

  if (tid < TT) {
    const int t = tid;
    float mean = 0.f;
    for (int c = 0; c < CC; ++c) mean += s_comb[c*CPAD + t];
    mean *= (1.f/CC);
    float var = 0.f;
    for (int c = 0; c < CC; ++c) { float dv = s_comb[c*CPAD + t] - mean; var += dv*dv; }
    var *= (1.f/CC);
    float rstd = 1.f / sqrtf(var + 1e-5f);
    for (int c = 0; c < CC; ++c) {
      float y = (s_comb[c*CPAD + t] - mean) * rstd * alpha[c] + beta[c];
      s_comb[c*CPAD + t] = y + x[bb + c*TT + t];
    }
  }
  __syncthreads();

  float* s_w = s_kv;
  for (int o = tid; o < TT*TT; o += 128) {
    int f = o / TT, t = o - f*TT;
    s_w[t*TT + f] = fcw[o];
  }
  __syncthreads();

  for (int o = tid; o < CC*TT; o += 128) {
    int c = o / TT, f = o - c*TT;
    const float* cr = s_comb + c*CPAD;
    float a0 = 0.f, a1 = 0.f;
    for (int t = 0; t < TT; t += 2) {
      a0 += cr[t    ] * s_w[(t    )*TT + f];
      a1 += cr[t + 1] * s_w[(t + 1)*TT + f];
    }
    out[bb + o] = tanhf(a0 + a1 + fcb[f]);
  }
}

// ---------------------------------------------------------------- launch
extern "C" void kernel_launch(void* const* d_in, const int* in_sizes, int n_in,
                              void* d_out, int out_size, void* d_ws, size_t ws_size,
                              hipStream_t stream) {
  const float* x     = (const float*)d_in[0];
  const float* adj   = (const float*)d_in[1];
  const float* sadj  = (const float*)d_in[2];
  const float* tmask = (const float*)d_in[3];
  const float* tadj  = (const float*)d_in[4];
  const float* st_wq = (const float*)d_in[5];  const float* st_bq = (const float*)d_in[6];
  const float* st_wk = (const float*)d_in[7];  const float* st_bk = (const float*)d_in[8];
  const float* st_wv = (const float*)d_in[9];  const float* st_bv = (const float*)d_in[10];
  const float* st_wo = (const float*)d_in[11]; const float* st_bo = (const float*)d_in[12];
  const float* ts_wq = (const float*)d_in[13]; const float* ts_bq = (const float*)d_in[14];
  const float* ts_wk = (const float*)d_in[15]; const float* ts_bk = (const float*)d_in[16];
  const float* ts_wv = (const float*)d_in[17]; const float* ts_bv = (const float*)d_in[18];
  const float* ts_wo = (const float*)d_in[19]; const float* ts_bo = (const float*)d_in[20];
  const float* alpha = (const float*)d_in[21]; const float* beta  = (const float*)d_in[22];
  const float* fcw   = (const float*)d_in[23]; const float* fcb   = (const float*)d_in[24];
  float* out = (float*)d_out;

  const int B = in_sizes[0] / (CC*TT);
  const size_t w_bytes   = (size_t)W_TOTAL * 2 + 1024;   // + bias2 floats
  const size_t spt_bytes = (size_t)B * SPT_R * SPT_S * 2;
  const size_t tp_bytes  = (size_t)B * TP_R * TP_S * 2;
  const size_t need = w_bytes + spt_bytes + tp_bytes;

  if (ws_size >= need) {
    bf16*  wsec    = (bf16*)d_ws;
    float* bias2   = (float*)((char*)d_ws + (size_t)W_TOTAL*2);
    bf16*  spT_all = (bf16*)((char*)d_ws + w_bytes);
    bf16*  tp_all  = spT_all + (size_t)B * SPT_R * SPT_S;

    k_wprep<<<1553, 256, 0, stream>>>(st_wk, st_wq, ts_wk, ts_wq,
                                      st_wv, st_wo, ts_wv, ts_wo,
                                      st_bo, st_bv, ts_bo, ts_bv,
                                      wsec, bias2);
    k_prep<<<B, 256, 0, stream>>>(x, adj, sadj, tmask, tadj, spT_all, tp_all);
    k_attn2<<<B, 1024, 0, stream>>>(spT_all, tp_all, wsec, st_bq, ts_bq,
                                    bias2, x, alpha, beta, fcw, fcb, out);
  } else {
    k_fused<<<B, 128, 0, stream>>>(x, adj, sadj, tmask, tadj,
                                   st_wq, st_bq, st_wk, st_bk, st_wv, st_bv, st_wo, st_bo,
                                   ts_wq, ts_bq, ts_wk, ts_bk, ts_wv, ts_bv, ts_wo, ts_bo,
                                   alpha, beta, fcw, fcb, out);
  }
}